// Round 1
// baseline (4519.183 us; speedup 1.0000x reference)
//
#include <hip/hip_runtime.h>
#include <math.h>

// ---------------------------------------------------------------------------
// JPEG-domain ViT, fp32 correctness baseline.
// Pipeline: preproc (RGB->YUV, 8x8 DCT, zigzag mask, tokenize)
//           6 x [LN -> qkv GEMM -> attention -> wo GEMM(+res) -> LN -> w1 GEMM(+GELU) -> w2 GEMM(+res)]
//           postproc (de-tokenize, "inverse" DCT = D*C*D^T per reference, YUV->RGB)
// All GEMMs are classic 64x64-tile fp32 LDS kernels (round 0; MFMA comes next).
// ---------------------------------------------------------------------------

#define NIMG 16
#define SEQ 192
#define DIMV 1024
#define MROWS (NIMG * SEQ)   // 3072

__constant__ float DCT8c[8][8] = {
  { 0.35355339f, 0.35355339f, 0.35355339f, 0.35355339f, 0.35355339f, 0.35355339f, 0.35355339f, 0.35355339f},
  { 0.49039264f, 0.41573481f, 0.27778512f, 0.09754516f,-0.09754516f,-0.27778512f,-0.41573481f,-0.49039264f},
  { 0.46193977f, 0.19134172f,-0.19134172f,-0.46193977f,-0.46193977f,-0.19134172f, 0.19134172f, 0.46193977f},
  { 0.41573481f,-0.09754516f,-0.49039264f,-0.27778512f, 0.27778512f, 0.49039264f, 0.09754516f,-0.41573481f},
  { 0.35355339f,-0.35355339f,-0.35355339f, 0.35355339f, 0.35355339f,-0.35355339f,-0.35355339f, 0.35355339f},
  { 0.27778512f,-0.49039264f, 0.09754516f, 0.41573481f,-0.41573481f,-0.09754516f, 0.49039264f,-0.27778512f},
  { 0.19134172f,-0.46193977f, 0.46193977f,-0.19134172f,-0.19134172f, 0.46193977f,-0.46193977f, 0.19134172f},
  { 0.09754516f,-0.27778512f, 0.41573481f,-0.49039264f, 0.49039264f,-0.41573481f, 0.27778512f,-0.09754516f}
};

// ---------------- preprocess: img -> tokens x[n, s=c*64+p*8+q, l=hb*32+wb] ----
__global__ void preproc_k(const float* __restrict__ img, float* __restrict__ x0) {
  int bid = blockIdx.x;
  int wb = bid & 31, hb = (bid >> 5) & 31, n = bid >> 10;
  int t = threadIdx.x, i = t >> 3, j = t & 7;
  __shared__ float blk[3][8][8];
  __shared__ float tmp[3][8][8];
  size_t pix = ((size_t)(n * 3) * 256 + hb * 8 + i) * 256 + wb * 8 + j;
  float r = img[pix], g = img[pix + 65536], b = img[pix + 131072];
  blk[0][i][j] =  0.299f   * r + 0.587f   * g + 0.114f   * b;
  blk[1][i][j] = -0.14713f * r - 0.28886f * g + 0.436f   * b;
  blk[2][i][j] =  0.615f   * r - 0.51499f * g - 0.10001f * b;
  __syncthreads();
  // tmp[c][p][j] = sum_i D[p][i] * blk[c][i][j]   (thread index i plays p)
  #pragma unroll
  for (int c = 0; c < 3; ++c) {
    float a = 0.f;
    #pragma unroll
    for (int k = 0; k < 8; ++k) a += DCT8c[i][k] * blk[c][k][j];
    tmp[c][i][j] = a;
  }
  __syncthreads();
  int l = hb * 32 + wb;
  #pragma unroll
  for (int c = 0; c < 3; ++c) {
    float a = 0.f;
    #pragma unroll
    for (int k = 0; k < 8; ++k) a += tmp[c][i][k] * DCT8c[j][k];
    // zigzag keep mask: Y keep 25, U/V keep 9
    float mk;
    if (c == 0) mk = ((i + j) <= 5 || ((i + j) == 6 && j < 4)) ? 1.f : 0.f;
    else        mk = ((i + j) <= 2 || ((i + j) == 3 && i < 3)) ? 1.f : 0.f;
    x0[((size_t)(n * SEQ + c * 64 + t)) * DIMV + l] = a * mk;
  }
}

// ---------------- postprocess: tokens -> rec = D*C*D^T -> YUV->RGB ----------
__global__ void postproc_k(const float* __restrict__ x, float* __restrict__ out) {
  int bid = blockIdx.x;
  int wb = bid & 31, hb = (bid >> 5) & 31, n = bid >> 10;
  int t = threadIdx.x, i = t >> 3, j = t & 7;
  __shared__ float cf[3][8][8];
  __shared__ float tmp[3][8][8];
  int l = hb * 32 + wb;
  #pragma unroll
  for (int c = 0; c < 3; ++c)
    cf[c][i][j] = x[((size_t)(n * SEQ + c * 64 + t)) * DIMV + l];
  __syncthreads();
  #pragma unroll
  for (int c = 0; c < 3; ++c) {
    float a = 0.f;
    #pragma unroll
    for (int k = 0; k < 8; ++k) a += DCT8c[i][k] * cf[c][k][j];
    tmp[c][i][j] = a;
  }
  __syncthreads();
  float a0 = 0.f, a1 = 0.f, a2 = 0.f;
  #pragma unroll
  for (int k = 0; k < 8; ++k) {
    a0 += tmp[0][i][k] * DCT8c[j][k];
    a1 += tmp[1][i][k] * DCT8c[j][k];
    a2 += tmp[2][i][k] * DCT8c[j][k];
  }
  size_t pix = ((size_t)(n * 3) * 256 + hb * 8 + i) * 256 + wb * 8 + j;
  out[pix]          = a0 + 1.13983f * a2;
  out[pix + 65536]  = a0 - 0.39465f * a1 - 0.5806f * a2;
  out[pix + 131072] = a0 + 2.03211f * a1;
}

// ---------------- layernorm over last dim (1024), one block per row --------
__global__ __launch_bounds__(256) void ln_k(const float* __restrict__ x,
                                            const float* __restrict__ g,
                                            const float* __restrict__ b,
                                            float* __restrict__ out) {
  int row = blockIdx.x, t = threadIdx.x;
  float4 v = ((const float4*)(x + (size_t)row * DIMV))[t];
  float s  = v.x + v.y + v.z + v.w;
  float s2 = v.x * v.x + v.y * v.y + v.z * v.z + v.w * v.w;
  #pragma unroll
  for (int off = 32; off > 0; off >>= 1) {
    s  += __shfl_down(s,  off, 64);
    s2 += __shfl_down(s2, off, 64);
  }
  __shared__ float red[8];
  int w = t >> 6;
  if ((t & 63) == 0) { red[w] = s; red[4 + w] = s2; }
  __syncthreads();
  s  = red[0] + red[1] + red[2] + red[3];
  s2 = red[4] + red[5] + red[6] + red[7];
  float mu  = s * (1.f / 1024.f);
  float var = fmaxf(s2 * (1.f / 1024.f) - mu * mu, 0.f);
  float rs  = rsqrtf(var + 1e-5f);
  float4 gv = ((const float4*)g)[t];
  float4 bv = ((const float4*)b)[t];
  float4 ov;
  ov.x = (v.x - mu) * rs * gv.x + bv.x;
  ov.y = (v.y - mu) * rs * gv.y + bv.y;
  ov.z = (v.z - mu) * rs * gv.z + bv.z;
  ov.w = (v.w - mu) * rs * gv.w + bv.w;
  ((float4*)(out + (size_t)row * DIMV))[t] = ov;
}

// ---------------- fp32 tiled GEMM: C[M,N] = A[M,K] @ B[K,N] (+epilogue) ----
// EPI: 0 = plain, 1 = +bias +residual, 2 = +bias +exact GELU
template <int EPI>
__global__ __launch_bounds__(256) void gemm_k(const float* __restrict__ A,
                                              const float* __restrict__ B,
                                              const float* __restrict__ bias,
                                              const float* __restrict__ res,
                                              float* __restrict__ C,
                                              int M, int N, int K) {
  __shared__ float As[16][72];  // [k][m], row stride 72 keeps float4 alignment
  __shared__ float Bs[16][72];  // [k][n]
  int t = threadIdx.x;
  int tx = t & 15, ty = t >> 4;
  int m0 = blockIdx.y << 6, n0 = blockIdx.x << 6;
  int arow = t >> 2,  acol = (t & 3) << 2;
  int brow = t >> 4,  bcol = (t & 15) << 2;
  const float* Ap = A + (size_t)(m0 + arow) * K + acol;
  const float* Bp = B + (size_t)brow * N + n0 + bcol;
  float acc[4][4] = {};
  for (int k0 = 0; k0 < K; k0 += 16) {
    float4 av = *(const float4*)(Ap + k0);
    float4 bv = *(const float4*)(Bp + (size_t)k0 * N);
    __syncthreads();
    As[acol + 0][arow] = av.x; As[acol + 1][arow] = av.y;
    As[acol + 2][arow] = av.z; As[acol + 3][arow] = av.w;
    *(float4*)&Bs[brow][bcol] = bv;
    __syncthreads();
    #pragma unroll
    for (int kk = 0; kk < 16; ++kk) {
      float4 a = *(const float4*)&As[kk][ty << 2];
      float4 b = *(const float4*)&Bs[kk][tx << 2];
      acc[0][0] += a.x*b.x; acc[0][1] += a.x*b.y; acc[0][2] += a.x*b.z; acc[0][3] += a.x*b.w;
      acc[1][0] += a.y*b.x; acc[1][1] += a.y*b.y; acc[1][2] += a.y*b.z; acc[1][3] += a.y*b.w;
      acc[2][0] += a.z*b.x; acc[2][1] += a.z*b.y; acc[2][2] += a.z*b.z; acc[2][3] += a.z*b.w;
      acc[3][0] += a.w*b.x; acc[3][1] += a.w*b.y; acc[3][2] += a.w*b.z; acc[3][3] += a.w*b.w;
    }
  }
  #pragma unroll
  for (int u = 0; u < 4; ++u) {
    int row = m0 + (ty << 2) + u;
    int col = n0 + (tx << 2);
    float4 cv = make_float4(acc[u][0], acc[u][1], acc[u][2], acc[u][3]);
    if (EPI >= 1) {
      cv.x += bias[col]; cv.y += bias[col + 1]; cv.z += bias[col + 2]; cv.w += bias[col + 3];
    }
    if (EPI == 1) {
      float4 rv = *(const float4*)(res + (size_t)row * N + col);
      cv.x += rv.x; cv.y += rv.y; cv.z += rv.z; cv.w += rv.w;
    }
    if (EPI == 2) {
      cv.x = 0.5f * cv.x * (1.f + erff(cv.x * 0.70710678f));
      cv.y = 0.5f * cv.y * (1.f + erff(cv.y * 0.70710678f));
      cv.z = 0.5f * cv.z * (1.f + erff(cv.z * 0.70710678f));
      cv.w = 0.5f * cv.w * (1.f + erff(cv.w * 0.70710678f));
    }
    *(float4*)(C + (size_t)row * N + col) = cv;
  }
}

// ---------------- attention: one block per (n,h), thread = query row --------
// qkv[n, s, 1536]: q = cols 0..511, k = 512..1023, v = 1024..1535 (h*64 slice)
__global__ __launch_bounds__(192) void attn_k(const float* __restrict__ qkv,
                                              float* __restrict__ o) {
  int n = blockIdx.x >> 3, h = blockIdx.x & 7;
  int t = threadIdx.x;  // query index 0..191
  __shared__ float Ks[96][64];
  __shared__ float Vs[96][64];
  const float* base = qkv + (size_t)n * SEQ * 1536;
  float4 q4[16];
  #pragma unroll
  for (int u = 0; u < 16; ++u) {
    float4 qv = *(const float4*)(base + (size_t)t * 1536 + h * 64 + u * 4);
    qv.x *= 0.125f; qv.y *= 0.125f; qv.z *= 0.125f; qv.w *= 0.125f;  // fold scale
    q4[u] = qv;
  }
  float4 oa[16];
  #pragma unroll
  for (int u = 0; u < 16; ++u) oa[u] = make_float4(0.f, 0.f, 0.f, 0.f);
  float mmax = -3.0e38f, lsum = 0.f;
  for (int tile = 0; tile < 2; ++tile) {
    __syncthreads();
    #pragma unroll
    for (int u = 0; u < 8; ++u) {
      int idx = u * 192 + t;
      int row = idx >> 4, c4 = (idx & 15) << 2;
      const float* src = base + (size_t)(tile * 96 + row) * 1536 + h * 64;
      *(float4*)&Ks[row][c4] = *(const float4*)(src + 512 + c4);
      *(float4*)&Vs[row][c4] = *(const float4*)(src + 1024 + c4);
    }
    __syncthreads();
    for (int m = 0; m < 96; ++m) {
      const float4* kr = (const float4*)Ks[m];
      float s = 0.f;
      #pragma unroll
      for (int u = 0; u < 16; ++u) {
        float4 kv = kr[u];
        s += q4[u].x * kv.x + q4[u].y * kv.y + q4[u].z * kv.z + q4[u].w * kv.w;
      }
      if (s > mmax) {  // online softmax rescale (rare on random data)
        float corr = __expf(mmax - s);
        lsum *= corr;
        #pragma unroll
        for (int u = 0; u < 16; ++u) {
          oa[u].x *= corr; oa[u].y *= corr; oa[u].z *= corr; oa[u].w *= corr;
        }
        mmax = s;
      }
      float p = __expf(s - mmax);
      lsum += p;
      const float4* vr = (const float4*)Vs[m];
      #pragma unroll
      for (int u = 0; u < 16; ++u) {
        float4 vv = vr[u];
        oa[u].x += p * vv.x; oa[u].y += p * vv.y; oa[u].z += p * vv.z; oa[u].w += p * vv.w;
      }
    }
  }
  float inv = 1.f / lsum;
  float* dst = o + (size_t)(n * SEQ + t) * 512 + h * 64;
  #pragma unroll
  for (int u = 0; u < 16; ++u) {
    float4 ov = oa[u];
    ov.x *= inv; ov.y *= inv; ov.z *= inv; ov.w *= inv;
    *(float4*)(dst + u * 4) = ov;
  }
}

// ---------------------------------------------------------------------------
extern "C" void kernel_launch(void* const* d_in, const int* in_sizes, int n_in,
                              void* d_out, int out_size, void* d_ws, size_t ws_size,
                              hipStream_t stream) {
  const float* img   = (const float*)d_in[0];
  const float* ln1_g = (const float*)d_in[1];
  const float* ln1_b = (const float*)d_in[2];
  const float* wqkv  = (const float*)d_in[3];
  const float* wo    = (const float*)d_in[4];
  const float* bo    = (const float*)d_in[5];
  const float* ln2_g = (const float*)d_in[6];
  const float* ln2_b = (const float*)d_in[7];
  const float* w1    = (const float*)d_in[8];
  const float* b1    = (const float*)d_in[9];
  const float* w2    = (const float*)d_in[10];
  const float* b2    = (const float*)d_in[11];
  float* out = (float*)d_out;

  // workspace layout (floats): x | xn | big(qkv/h union) | o  => 56.6 MB total
  float* ws  = (float*)d_ws;
  float* x   = ws;                                  // 3072*1024
  float* xn  = x  + (size_t)MROWS * DIMV;           // 3072*1024
  float* big = xn + (size_t)MROWS * DIMV;           // 3072*2048 (qkv needs 3072*1536)
  float* o   = big + (size_t)MROWS * 2048;          // 3072*512
  float* qkv = big;
  float* h   = big;

  preproc_k<<<16384, 64, 0, stream>>>(img, x);

  for (int l = 0; l < 6; ++l) {
    ln_k<<<MROWS, 256, 0, stream>>>(x, ln1_g + l * 1024, ln1_b + l * 1024, xn);
    gemm_k<0><<<dim3(1536 / 64, MROWS / 64), 256, 0, stream>>>(
        xn, wqkv + (size_t)l * 1024 * 1536, nullptr, nullptr, qkv, MROWS, 1536, 1024);
    attn_k<<<NIMG * 8, 192, 0, stream>>>(qkv, o);
    gemm_k<1><<<dim3(1024 / 64, MROWS / 64), 256, 0, stream>>>(
        o, wo + (size_t)l * 512 * 1024, bo + l * 1024, x, x, MROWS, 1024, 512);
    ln_k<<<MROWS, 256, 0, stream>>>(x, ln2_g + l * 1024, ln2_b + l * 1024, xn);
    gemm_k<2><<<dim3(2048 / 64, MROWS / 64), 256, 0, stream>>>(
        xn, w1 + (size_t)l * 1024 * 2048, b1 + l * 2048, nullptr, h, MROWS, 2048, 1024);
    gemm_k<1><<<dim3(1024 / 64, MROWS / 64), 256, 0, stream>>>(
        h, w2 + (size_t)l * 2048 * 1024, b2 + l * 1024, x, x, MROWS, 1024, 2048);
  }

  postproc_k<<<16384, 64, 0, stream>>>(x, out);
}

// Round 2
// 1758.348 us; speedup vs baseline: 2.5701x; 2.5701x over previous
//
#include <hip/hip_runtime.h>
#include <math.h>

// ---------------------------------------------------------------------------
// JPEG-domain ViT. Round 2: bf16 MFMA GEMMs (m97 structure: 128x128 tile,
// 16x16x32 MFMA, global_load_lds width-16, weights pre-transposed to [N][K]).
// Residual stream stays fp32; GEMM operands bf16.
// ---------------------------------------------------------------------------

#define NIMG 16
#define SEQ 192
#define DIMV 1024
#define MROWS (NIMG * SEQ)   // 3072

typedef __attribute__((ext_vector_type(8))) short short8v;
typedef __attribute__((ext_vector_type(4))) float f32x4;
typedef unsigned short ushort_t;
typedef unsigned int uint_t;

__device__ __forceinline__ unsigned short f2bf(float f) {
  union { float f; uint_t u; } x; x.f = f;
  uint_t r = x.u + 0x7fffu + ((x.u >> 16) & 1u);
  return (unsigned short)(r >> 16);
}
__device__ __forceinline__ float bf2f(unsigned short h) {
  union { uint_t u; float f; } y; y.u = ((uint_t)h) << 16;
  return y.f;
}

__device__ __forceinline__ void gload16(const void* g, void* l) {
  __builtin_amdgcn_global_load_lds(
      reinterpret_cast<const __attribute__((address_space(1))) void*>(
          reinterpret_cast<uintptr_t>(g)),
      reinterpret_cast<__attribute__((address_space(3))) void*>(
          reinterpret_cast<uintptr_t>(l)),
      16, 0, 0);
}

__constant__ float DCT8c[8][8] = {
  { 0.35355339f, 0.35355339f, 0.35355339f, 0.35355339f, 0.35355339f, 0.35355339f, 0.35355339f, 0.35355339f},
  { 0.49039264f, 0.41573481f, 0.27778512f, 0.09754516f,-0.09754516f,-0.27778512f,-0.41573481f,-0.49039264f},
  { 0.46193977f, 0.19134172f,-0.19134172f,-0.46193977f,-0.46193977f,-0.19134172f, 0.19134172f, 0.46193977f},
  { 0.41573481f,-0.09754516f,-0.49039264f,-0.27778512f, 0.27778512f, 0.49039264f, 0.09754516f,-0.41573481f},
  { 0.35355339f,-0.35355339f,-0.35355339f, 0.35355339f, 0.35355339f,-0.35355339f,-0.35355339f, 0.35355339f},
  { 0.27778512f,-0.49039264f, 0.09754516f, 0.41573481f,-0.41573481f,-0.09754516f, 0.49039264f,-0.27778512f},
  { 0.19134172f,-0.46193977f, 0.46193977f,-0.19134172f,-0.19134172f, 0.46193977f,-0.46193977f, 0.19134172f},
  { 0.09754516f,-0.27778512f, 0.41573481f,-0.49039264f, 0.49039264f,-0.41573481f, 0.27778512f,-0.09754516f}
};

// ---------------- preprocess: img -> tokens x[n, s=c*64+p*8+q, l=hb*32+wb] ----
__global__ void preproc_k(const float* __restrict__ img, float* __restrict__ x0) {
  int bid = blockIdx.x;
  int wb = bid & 31, hb = (bid >> 5) & 31, n = bid >> 10;
  int t = threadIdx.x, i = t >> 3, j = t & 7;
  __shared__ float blk[3][8][8];
  __shared__ float tmp[3][8][8];
  size_t pix = ((size_t)(n * 3) * 256 + hb * 8 + i) * 256 + wb * 8 + j;
  float r = img[pix], g = img[pix + 65536], b = img[pix + 131072];
  blk[0][i][j] =  0.299f   * r + 0.587f   * g + 0.114f   * b;
  blk[1][i][j] = -0.14713f * r - 0.28886f * g + 0.436f   * b;
  blk[2][i][j] =  0.615f   * r - 0.51499f * g - 0.10001f * b;
  __syncthreads();
  #pragma unroll
  for (int c = 0; c < 3; ++c) {
    float a = 0.f;
    #pragma unroll
    for (int k = 0; k < 8; ++k) a += DCT8c[i][k] * blk[c][k][j];
    tmp[c][i][j] = a;
  }
  __syncthreads();
  int l = hb * 32 + wb;
  #pragma unroll
  for (int c = 0; c < 3; ++c) {
    float a = 0.f;
    #pragma unroll
    for (int k = 0; k < 8; ++k) a += tmp[c][i][k] * DCT8c[j][k];
    float mk;
    if (c == 0) mk = ((i + j) <= 5 || ((i + j) == 6 && j < 4)) ? 1.f : 0.f;
    else        mk = ((i + j) <= 2 || ((i + j) == 3 && i < 3)) ? 1.f : 0.f;
    x0[((size_t)(n * SEQ + c * 64 + t)) * DIMV + l] = a * mk;
  }
}

// ---------------- postprocess: tokens -> rec = D*C*D^T -> YUV->RGB ----------
__global__ void postproc_k(const float* __restrict__ x, float* __restrict__ out) {
  int bid = blockIdx.x;
  int wb = bid & 31, hb = (bid >> 5) & 31, n = bid >> 10;
  int t = threadIdx.x, i = t >> 3, j = t & 7;
  __shared__ float cf[3][8][8];
  __shared__ float tmp[3][8][8];
  int l = hb * 32 + wb;
  #pragma unroll
  for (int c = 0; c < 3; ++c)
    cf[c][i][j] = x[((size_t)(n * SEQ + c * 64 + t)) * DIMV + l];
  __syncthreads();
  #pragma unroll
  for (int c = 0; c < 3; ++c) {
    float a = 0.f;
    #pragma unroll
    for (int k = 0; k < 8; ++k) a += DCT8c[i][k] * cf[c][k][j];
    tmp[c][i][j] = a;
  }
  __syncthreads();
  float a0 = 0.f, a1 = 0.f, a2 = 0.f;
  #pragma unroll
  for (int k = 0; k < 8; ++k) {
    a0 += tmp[0][i][k] * DCT8c[j][k];
    a1 += tmp[1][i][k] * DCT8c[j][k];
    a2 += tmp[2][i][k] * DCT8c[j][k];
  }
  size_t pix = ((size_t)(n * 3) * 256 + hb * 8 + i) * 256 + wb * 8 + j;
  out[pix]          = a0 + 1.13983f * a2;
  out[pix + 65536]  = a0 - 0.39465f * a1 - 0.5806f * a2;
  out[pix + 131072] = a0 + 2.03211f * a1;
}

// ---------------- weight transpose+convert: w[K][N] fp32 -> wt[N][K] bf16 ---
__global__ __launch_bounds__(256) void wconv_k(const float* __restrict__ w,
                                               unsigned short* __restrict__ wt,
                                               int K, int N) {
  __shared__ float s[32][33];
  int t = threadIdx.x;
  int n0 = blockIdx.x << 5, k0 = blockIdx.y << 5;
  int r = t >> 3, c4 = (t & 7) << 2;
  float4 v = *(const float4*)(w + (size_t)(k0 + r) * N + n0 + c4);
  s[r][c4] = v.x; s[r][c4 + 1] = v.y; s[r][c4 + 2] = v.z; s[r][c4 + 3] = v.w;
  __syncthreads();
  ushort4 o;
  o.x = f2bf(s[c4 + 0][r]); o.y = f2bf(s[c4 + 1][r]);
  o.z = f2bf(s[c4 + 2][r]); o.w = f2bf(s[c4 + 3][r]);
  *(ushort4*)(wt + (size_t)(n0 + r) * K + k0 + c4) = o;
}

// ---------------- layernorm over last dim (1024): fp32 in -> bf16 out -------
__global__ __launch_bounds__(256) void ln_k(const float* __restrict__ x,
                                            const float* __restrict__ g,
                                            const float* __restrict__ b,
                                            unsigned short* __restrict__ out) {
  int row = blockIdx.x, t = threadIdx.x;
  float4 v = ((const float4*)(x + (size_t)row * DIMV))[t];
  float s  = v.x + v.y + v.z + v.w;
  float s2 = v.x * v.x + v.y * v.y + v.z * v.z + v.w * v.w;
  #pragma unroll
  for (int off = 32; off > 0; off >>= 1) {
    s  += __shfl_down(s,  off, 64);
    s2 += __shfl_down(s2, off, 64);
  }
  __shared__ float red[8];
  int w = t >> 6;
  if ((t & 63) == 0) { red[w] = s; red[4 + w] = s2; }
  __syncthreads();
  s  = red[0] + red[1] + red[2] + red[3];
  s2 = red[4] + red[5] + red[6] + red[7];
  float mu  = s * (1.f / 1024.f);
  float var = fmaxf(s2 * (1.f / 1024.f) - mu * mu, 0.f);
  float rs  = rsqrtf(var + 1e-5f);
  float4 gv = ((const float4*)g)[t];
  float4 bv = ((const float4*)b)[t];
  ushort4 ov;
  ov.x = f2bf((v.x - mu) * rs * gv.x + bv.x);
  ov.y = f2bf((v.y - mu) * rs * gv.y + bv.y);
  ov.z = f2bf((v.z - mu) * rs * gv.z + bv.z);
  ov.w = f2bf((v.w - mu) * rs * gv.w + bv.w);
  ((ushort4*)(out + (size_t)row * DIMV))[t] = ov;
}

// ---------------- bf16 MFMA GEMM: C[M,N] = A[M,K] @ Bt[N,K]^T (+epilogue) ---
// m97 structure: 128x128 tile, 4 waves, each wave 64x64 via 4x4 16x16x32 MFMA.
// EPI: 0 = plain -> bf16 C, 1 = +bias +fp32 residual -> fp32 C, 2 = +bias +GELU -> bf16 C
template <int EPI>
__global__ __launch_bounds__(256) void mm_k(const unsigned short* __restrict__ A,
                                            const unsigned short* __restrict__ Bt,
                                            const float* __restrict__ bias,
                                            const float* res,
                                            void* Cout,
                                            int M, int N, int K) {
  __shared__ __align__(16) unsigned short As[128 * 32];
  __shared__ __align__(16) unsigned short Bs[128 * 32];
  int t = threadIdx.x;
  int lane = t & 63, w = t >> 6;
  int m0 = blockIdx.y << 7, n0 = blockIdx.x << 7;
  int wm = (w >> 1) << 6, wn = (w & 1) << 6;

  // staging: chunk c (0..7) = 16 rows x 64B; lane covers row c*16 + lane/4,
  // bytes (lane&3)*16 within the 64B (=32 bf16) row slice.
  int srow = lane >> 2;
  int selem = (lane & 3) << 3;       // element offset within 32-wide row slice
  const unsigned short* Ag = A + (size_t)(m0 + srow) * K + selem;
  const unsigned short* Bg = Bt + (size_t)(n0 + srow) * K + selem;

  f32x4 acc[4][4] = {};

  for (int k0 = 0; k0 < K; k0 += 32) {
    #pragma unroll
    for (int i = 0; i < 2; ++i) {
      int c = i * 4 + w;
      gload16(Ag + (size_t)(c << 4) * K + k0, (char*)As + (c << 10));
      gload16(Bg + (size_t)(c << 4) * K + k0, (char*)Bs + (c << 10));
    }
    __syncthreads();   // compiler emits vmcnt(0) drain here (m97 structure)
    short8v a[4], b[4];
    #pragma unroll
    for (int mi = 0; mi < 4; ++mi)
      a[mi] = *(const short8v*)&As[(wm + mi * 16 + (lane & 15)) * 32 + ((lane >> 4) << 3)];
    #pragma unroll
    for (int ni = 0; ni < 4; ++ni)
      b[ni] = *(const short8v*)&Bs[(wn + ni * 16 + (lane & 15)) * 32 + ((lane >> 4) << 3)];
    #pragma unroll
    for (int mi = 0; mi < 4; ++mi)
      #pragma unroll
      for (int ni = 0; ni < 4; ++ni)
        acc[mi][ni] = __builtin_amdgcn_mfma_f32_16x16x32_bf16(a[mi], b[ni], acc[mi][ni], 0, 0, 0);
    __syncthreads();
  }

  // epilogue: C/D frag layout col = lane&15, row = (lane>>4)*4 + r  [m89/m91]
  int cn = lane & 15;
  int rb = (lane >> 4) << 2;
  #pragma unroll
  for (int mi = 0; mi < 4; ++mi) {
    #pragma unroll
    for (int ni = 0; ni < 4; ++ni) {
      int col = n0 + wn + ni * 16 + cn;
      #pragma unroll
      for (int r = 0; r < 4; ++r) {
        int row = m0 + wm + mi * 16 + rb + r;
        float v = acc[mi][ni][r];
        if (EPI >= 1) v += bias[col];
        if (EPI == 1) {
          ((float*)Cout)[(size_t)row * N + col] = v + res[(size_t)row * N + col];
        } else if (EPI == 2) {
          v = 0.5f * v * (1.f + erff(v * 0.70710678f));
          ((unsigned short*)Cout)[(size_t)row * N + col] = f2bf(v);
        } else {
          ((unsigned short*)Cout)[(size_t)row * N + col] = f2bf(v);
        }
      }
    }
  }
}

// ---------------- attention: one block per (n,h), thread = query row --------
// qkv bf16 [n, s, 1536]: q cols 0..511, k 512..1023, v 1024..1535 (h*64 slice)
__global__ __launch_bounds__(192) void attn_k(const unsigned short* __restrict__ qkv,
                                              unsigned short* __restrict__ o) {
  int n = blockIdx.x >> 3, h = blockIdx.x & 7;
  int t = threadIdx.x;
  __shared__ float Ks[96][64];
  __shared__ float Vs[96][64];
  const unsigned short* base = qkv + (size_t)n * SEQ * 1536;
  float q[64];
  #pragma unroll
  for (int u = 0; u < 8; ++u) {
    uint4 raw = *(const uint4*)(base + (size_t)t * 1536 + h * 64 + u * 8);
    uint_t ww[4] = {raw.x, raw.y, raw.z, raw.w};
    #pragma unroll
    for (int i = 0; i < 4; ++i) {
      union { uint_t u; float f; } lo, hi;
      lo.u = ww[i] << 16; hi.u = ww[i] & 0xffff0000u;
      q[u * 8 + 2 * i]     = lo.f * 0.125f;
      q[u * 8 + 2 * i + 1] = hi.f * 0.125f;
    }
  }
  float oa[64];
  #pragma unroll
  for (int u = 0; u < 64; ++u) oa[u] = 0.f;
  float mmax = -3.0e38f, lsum = 0.f;
  for (int tile = 0; tile < 2; ++tile) {
    __syncthreads();
    #pragma unroll
    for (int u = 0; u < 4; ++u) {
      int idx = u * 192 + t;
      int row = idx >> 3, c8 = (idx & 7) << 3;
      const unsigned short* src = base + (size_t)(tile * 96 + row) * 1536 + h * 64;
      uint4 kr = *(const uint4*)(src + 512 + c8);
      uint4 vr = *(const uint4*)(src + 1024 + c8);
      uint_t kw[4] = {kr.x, kr.y, kr.z, kr.w};
      uint_t vw[4] = {vr.x, vr.y, vr.z, vr.w};
      #pragma unroll
      for (int i = 0; i < 4; ++i) {
        union { uint_t u; float f; } a, bq;
        a.u = kw[i] << 16;        Ks[row][c8 + 2 * i] = a.f;
        bq.u = kw[i] & 0xffff0000u; Ks[row][c8 + 2 * i + 1] = bq.f;
        a.u = vw[i] << 16;        Vs[row][c8 + 2 * i] = a.f;
        bq.u = vw[i] & 0xffff0000u; Vs[row][c8 + 2 * i + 1] = bq.f;
      }
    }
    __syncthreads();
    for (int m = 0; m < 96; ++m) {
      const float* kr = Ks[m];
      float s = 0.f;
      #pragma unroll
      for (int u = 0; u < 64; ++u) s += q[u] * kr[u];
      if (s > mmax) {
        float corr = __expf(mmax - s);
        lsum *= corr;
        #pragma unroll
        for (int u = 0; u < 64; ++u) oa[u] *= corr;
        mmax = s;
      }
      float p = __expf(s - mmax);
      lsum += p;
      const float* vr = Vs[m];
      #pragma unroll
      for (int u = 0; u < 64; ++u) oa[u] += p * vr[u];
    }
  }
  float inv = 1.f / lsum;
  unsigned short* dst = o + (size_t)(n * SEQ + t) * 512 + h * 64;
  #pragma unroll
  for (int u = 0; u < 16; ++u) {
    ushort4 ov;
    ov.x = f2bf(oa[u * 4 + 0] * inv);
    ov.y = f2bf(oa[u * 4 + 1] * inv);
    ov.z = f2bf(oa[u * 4 + 2] * inv);
    ov.w = f2bf(oa[u * 4 + 3] * inv);
    *(ushort4*)(dst + u * 4) = ov;
  }
}

// ---------------------------------------------------------------------------
extern "C" void kernel_launch(void* const* d_in, const int* in_sizes, int n_in,
                              void* d_out, int out_size, void* d_ws, size_t ws_size,
                              hipStream_t stream) {
  const float* img   = (const float*)d_in[0];
  const float* ln1_g = (const float*)d_in[1];
  const float* ln1_b = (const float*)d_in[2];
  const float* wqkv  = (const float*)d_in[3];
  const float* wo    = (const float*)d_in[4];
  const float* bo    = (const float*)d_in[5];
  const float* ln2_g = (const float*)d_in[6];
  const float* ln2_b = (const float*)d_in[7];
  const float* w1    = (const float*)d_in[8];
  const float* b1    = (const float*)d_in[9];
  const float* w2    = (const float*)d_in[10];
  const float* b2    = (const float*)d_in[11];
  float* out = (float*)d_out;

  // workspace layout (bytes), total 47.2 MB:
  char* ws = (char*)d_ws;
  float*          x      = (float*)ws;                         // 12,582,912
  unsigned short* xn     = (unsigned short*)(ws + 12582912);   //  6,291,456
  unsigned short* big    = (unsigned short*)(ws + 18874368);   // 12,582,912 (qkv 9.4MB / h 12.6MB union)
  unsigned short* ob     = (unsigned short*)(ws + 31457280);   //  3,145,728
  unsigned short* wt_qkv = (unsigned short*)(ws + 34603008);   //  3,145,728
  unsigned short* wt_o   = (unsigned short*)(ws + 37748736);   //  1,048,576
  unsigned short* wt_1   = (unsigned short*)(ws + 38797312);   //  4,194,304
  unsigned short* wt_2   = (unsigned short*)(ws + 42991616);   //  4,194,304

  preproc_k<<<16384, 64, 0, stream>>>(img, x);

  for (int l = 0; l < 6; ++l) {
    wconv_k<<<dim3(1536 / 32, 1024 / 32), 256, 0, stream>>>(wqkv + (size_t)l * 1024 * 1536, wt_qkv, 1024, 1536);
    wconv_k<<<dim3(1024 / 32,  512 / 32), 256, 0, stream>>>(wo   + (size_t)l *  512 * 1024, wt_o,    512, 1024);
    wconv_k<<<dim3(2048 / 32, 1024 / 32), 256, 0, stream>>>(w1   + (size_t)l * 1024 * 2048, wt_1,   1024, 2048);
    wconv_k<<<dim3(1024 / 32, 2048 / 32), 256, 0, stream>>>(w2   + (size_t)l * 2048 * 1024, wt_2,   2048, 1024);

    ln_k<<<MROWS, 256, 0, stream>>>(x, ln1_g + l * 1024, ln1_b + l * 1024, xn);
    mm_k<0><<<dim3(12, 24), 256, 0, stream>>>(xn, wt_qkv, nullptr, nullptr, big, MROWS, 1536, 1024);
    attn_k<<<NIMG * 8, 192, 0, stream>>>(big, ob);
    mm_k<1><<<dim3(8, 24), 256, 0, stream>>>(ob, wt_o, bo + l * 1024, x, x, MROWS, 1024, 512);
    ln_k<<<MROWS, 256, 0, stream>>>(x, ln2_g + l * 1024, ln2_b + l * 1024, xn);
    mm_k<2><<<dim3(16, 24), 256, 0, stream>>>(xn, wt_1, b1 + l * 2048, nullptr, big, MROWS, 2048, 1024);
    mm_k<1><<<dim3(8, 24), 256, 0, stream>>>(big, wt_2, b2 + l * 1024, x, x, MROWS, 1024, 2048);
  }

  postproc_k<<<16384, 64, 0, stream>>>(x, out);
}

// Round 3
// 1099.584 us; speedup vs baseline: 4.1099x; 1.5991x over previous
//
#include <hip/hip_runtime.h>
#include <math.h>

// ---------------------------------------------------------------------------
// JPEG-domain ViT. Round 3: MFMA flash-style attention (one 16-row Q tile per
// wave, K/V^T staged in XOR-swizzled LDS, exact single-pass softmax).
// GEMMs stay in the round-2 m97 structure (128x128 bf16 MFMA tiles).
// ---------------------------------------------------------------------------

#define NIMG 16
#define SEQ 192
#define DIMV 1024
#define MROWS (NIMG * SEQ)   // 3072

typedef __attribute__((ext_vector_type(8))) short short8v;
typedef __attribute__((ext_vector_type(4))) float f32x4;
typedef unsigned int uint_t;

__device__ __forceinline__ unsigned short f2bf(float f) {
  union { float f; uint_t u; } x; x.f = f;
  uint_t r = x.u + 0x7fffu + ((x.u >> 16) & 1u);
  return (unsigned short)(r >> 16);
}

__device__ __forceinline__ void gload16(const void* g, void* l) {
  __builtin_amdgcn_global_load_lds(
      reinterpret_cast<const __attribute__((address_space(1))) void*>(
          reinterpret_cast<uintptr_t>(g)),
      reinterpret_cast<__attribute__((address_space(3))) void*>(
          reinterpret_cast<uintptr_t>(l)),
      16, 0, 0);
}

__constant__ float DCT8c[8][8] = {
  { 0.35355339f, 0.35355339f, 0.35355339f, 0.35355339f, 0.35355339f, 0.35355339f, 0.35355339f, 0.35355339f},
  { 0.49039264f, 0.41573481f, 0.27778512f, 0.09754516f,-0.09754516f,-0.27778512f,-0.41573481f,-0.49039264f},
  { 0.46193977f, 0.19134172f,-0.19134172f,-0.46193977f,-0.46193977f,-0.19134172f, 0.19134172f, 0.46193977f},
  { 0.41573481f,-0.09754516f,-0.49039264f,-0.27778512f, 0.27778512f, 0.49039264f, 0.09754516f,-0.41573481f},
  { 0.35355339f,-0.35355339f,-0.35355339f, 0.35355339f, 0.35355339f,-0.35355339f,-0.35355339f, 0.35355339f},
  { 0.27778512f,-0.49039264f, 0.09754516f, 0.41573481f,-0.41573481f,-0.09754516f, 0.49039264f,-0.27778512f},
  { 0.19134172f,-0.46193977f, 0.46193977f,-0.19134172f,-0.19134172f, 0.46193977f,-0.46193977f, 0.19134172f},
  { 0.09754516f,-0.27778512f, 0.41573481f,-0.49039264f, 0.49039264f,-0.41573481f, 0.27778512f,-0.09754516f}
};

// ---------------- preprocess: img -> tokens x[n, s=c*64+p*8+q, l=hb*32+wb] ----
__global__ void preproc_k(const float* __restrict__ img, float* __restrict__ x0) {
  int bid = blockIdx.x;
  int wb = bid & 31, hb = (bid >> 5) & 31, n = bid >> 10;
  int t = threadIdx.x, i = t >> 3, j = t & 7;
  __shared__ float blk[3][8][8];
  __shared__ float tmp[3][8][8];
  size_t pix = ((size_t)(n * 3) * 256 + hb * 8 + i) * 256 + wb * 8 + j;
  float r = img[pix], g = img[pix + 65536], b = img[pix + 131072];
  blk[0][i][j] =  0.299f   * r + 0.587f   * g + 0.114f   * b;
  blk[1][i][j] = -0.14713f * r - 0.28886f * g + 0.436f   * b;
  blk[2][i][j] =  0.615f   * r - 0.51499f * g - 0.10001f * b;
  __syncthreads();
  #pragma unroll
  for (int c = 0; c < 3; ++c) {
    float a = 0.f;
    #pragma unroll
    for (int k = 0; k < 8; ++k) a += DCT8c[i][k] * blk[c][k][j];
    tmp[c][i][j] = a;
  }
  __syncthreads();
  int l = hb * 32 + wb;
  #pragma unroll
  for (int c = 0; c < 3; ++c) {
    float a = 0.f;
    #pragma unroll
    for (int k = 0; k < 8; ++k) a += tmp[c][i][k] * DCT8c[j][k];
    float mk;
    if (c == 0) mk = ((i + j) <= 5 || ((i + j) == 6 && j < 4)) ? 1.f : 0.f;
    else        mk = ((i + j) <= 2 || ((i + j) == 3 && i < 3)) ? 1.f : 0.f;
    x0[((size_t)(n * SEQ + c * 64 + t)) * DIMV + l] = a * mk;
  }
}

// ---------------- postprocess: tokens -> rec = D*C*D^T -> YUV->RGB ----------
__global__ void postproc_k(const float* __restrict__ x, float* __restrict__ out) {
  int bid = blockIdx.x;
  int wb = bid & 31, hb = (bid >> 5) & 31, n = bid >> 10;
  int t = threadIdx.x, i = t >> 3, j = t & 7;
  __shared__ float cf[3][8][8];
  __shared__ float tmp[3][8][8];
  int l = hb * 32 + wb;
  #pragma unroll
  for (int c = 0; c < 3; ++c)
    cf[c][i][j] = x[((size_t)(n * SEQ + c * 64 + t)) * DIMV + l];
  __syncthreads();
  #pragma unroll
  for (int c = 0; c < 3; ++c) {
    float a = 0.f;
    #pragma unroll
    for (int k = 0; k < 8; ++k) a += DCT8c[i][k] * cf[c][k][j];
    tmp[c][i][j] = a;
  }
  __syncthreads();
  float a0 = 0.f, a1 = 0.f, a2 = 0.f;
  #pragma unroll
  for (int k = 0; k < 8; ++k) {
    a0 += tmp[0][i][k] * DCT8c[j][k];
    a1 += tmp[1][i][k] * DCT8c[j][k];
    a2 += tmp[2][i][k] * DCT8c[j][k];
  }
  size_t pix = ((size_t)(n * 3) * 256 + hb * 8 + i) * 256 + wb * 8 + j;
  out[pix]          = a0 + 1.13983f * a2;
  out[pix + 65536]  = a0 - 0.39465f * a1 - 0.5806f * a2;
  out[pix + 131072] = a0 + 2.03211f * a1;
}

// ---------------- weight transpose+convert: w[K][N] fp32 -> wt[N][K] bf16 ---
// blockIdx.z = layer (stride K*N on both sides)
__global__ __launch_bounds__(256) void wconv_k(const float* __restrict__ w,
                                               unsigned short* __restrict__ wt,
                                               int K, int N) {
  size_t off = (size_t)blockIdx.z * K * N;
  w += off; wt += off;
  __shared__ float s[32][33];
  int t = threadIdx.x;
  int n0 = blockIdx.x << 5, k0 = blockIdx.y << 5;
  int r = t >> 3, c4 = (t & 7) << 2;
  float4 v = *(const float4*)(w + (size_t)(k0 + r) * N + n0 + c4);
  s[r][c4] = v.x; s[r][c4 + 1] = v.y; s[r][c4 + 2] = v.z; s[r][c4 + 3] = v.w;
  __syncthreads();
  ushort4 o;
  o.x = f2bf(s[c4 + 0][r]); o.y = f2bf(s[c4 + 1][r]);
  o.z = f2bf(s[c4 + 2][r]); o.w = f2bf(s[c4 + 3][r]);
  *(ushort4*)(wt + (size_t)(n0 + r) * K + k0 + c4) = o;
}

// ---------------- layernorm over last dim (1024): fp32 in -> bf16 out -------
__global__ __launch_bounds__(256) void ln_k(const float* __restrict__ x,
                                            const float* __restrict__ g,
                                            const float* __restrict__ b,
                                            unsigned short* __restrict__ out) {
  int row = blockIdx.x, t = threadIdx.x;
  float4 v = ((const float4*)(x + (size_t)row * DIMV))[t];
  float s  = v.x + v.y + v.z + v.w;
  float s2 = v.x * v.x + v.y * v.y + v.z * v.z + v.w * v.w;
  #pragma unroll
  for (int off = 32; off > 0; off >>= 1) {
    s  += __shfl_down(s,  off, 64);
    s2 += __shfl_down(s2, off, 64);
  }
  __shared__ float red[8];
  int w = t >> 6;
  if ((t & 63) == 0) { red[w] = s; red[4 + w] = s2; }
  __syncthreads();
  s  = red[0] + red[1] + red[2] + red[3];
  s2 = red[4] + red[5] + red[6] + red[7];
  float mu  = s * (1.f / 1024.f);
  float var = fmaxf(s2 * (1.f / 1024.f) - mu * mu, 0.f);
  float rs  = rsqrtf(var + 1e-5f);
  float4 gv = ((const float4*)g)[t];
  float4 bv = ((const float4*)b)[t];
  ushort4 ov;
  ov.x = f2bf((v.x - mu) * rs * gv.x + bv.x);
  ov.y = f2bf((v.y - mu) * rs * gv.y + bv.y);
  ov.z = f2bf((v.z - mu) * rs * gv.z + bv.z);
  ov.w = f2bf((v.w - mu) * rs * gv.w + bv.w);
  ((ushort4*)(out + (size_t)row * DIMV))[t] = ov;
}

// ---------------- bf16 MFMA GEMM: C[M,N] = A[M,K] @ Bt[N,K]^T (+epilogue) ---
template <int EPI>
__global__ __launch_bounds__(256) void mm_k(const unsigned short* __restrict__ A,
                                            const unsigned short* __restrict__ Bt,
                                            const float* __restrict__ bias,
                                            const float* res,
                                            void* Cout,
                                            int M, int N, int K) {
  __shared__ __align__(16) unsigned short As[128 * 32];
  __shared__ __align__(16) unsigned short Bs[128 * 32];
  int t = threadIdx.x;
  int lane = t & 63, w = t >> 6;
  int m0 = blockIdx.y << 7, n0 = blockIdx.x << 7;
  int wm = (w >> 1) << 6, wn = (w & 1) << 6;
  int srow = lane >> 2;
  int selem = (lane & 3) << 3;
  const unsigned short* Ag = A + (size_t)(m0 + srow) * K + selem;
  const unsigned short* Bg = Bt + (size_t)(n0 + srow) * K + selem;

  f32x4 acc[4][4] = {};

  for (int k0 = 0; k0 < K; k0 += 32) {
    #pragma unroll
    for (int i = 0; i < 2; ++i) {
      int c = i * 4 + w;
      gload16(Ag + (size_t)(c << 4) * K + k0, (char*)As + (c << 10));
      gload16(Bg + (size_t)(c << 4) * K + k0, (char*)Bs + (c << 10));
    }
    __syncthreads();
    short8v a[4], b[4];
    #pragma unroll
    for (int mi = 0; mi < 4; ++mi)
      a[mi] = *(const short8v*)&As[(wm + mi * 16 + (lane & 15)) * 32 + ((lane >> 4) << 3)];
    #pragma unroll
    for (int ni = 0; ni < 4; ++ni)
      b[ni] = *(const short8v*)&Bs[(wn + ni * 16 + (lane & 15)) * 32 + ((lane >> 4) << 3)];
    #pragma unroll
    for (int mi = 0; mi < 4; ++mi)
      #pragma unroll
      for (int ni = 0; ni < 4; ++ni)
        acc[mi][ni] = __builtin_amdgcn_mfma_f32_16x16x32_bf16(a[mi], b[ni], acc[mi][ni], 0, 0, 0);
    __syncthreads();
  }

  int cn = lane & 15;
  int rb = (lane >> 4) << 2;
  #pragma unroll
  for (int mi = 0; mi < 4; ++mi) {
    #pragma unroll
    for (int ni = 0; ni < 4; ++ni) {
      int col = n0 + wn + ni * 16 + cn;
      #pragma unroll
      for (int r = 0; r < 4; ++r) {
        int row = m0 + wm + mi * 16 + rb + r;
        float v = acc[mi][ni][r];
        if (EPI >= 1) v += bias[col];
        if (EPI == 1) {
          ((float*)Cout)[(size_t)row * N + col] = v + res[(size_t)row * N + col];
        } else if (EPI == 2) {
          v = 0.5f * v * (1.f + erff(v * 0.70710678f));
          ((unsigned short*)Cout)[(size_t)row * N + col] = f2bf(v);
        } else {
          ((unsigned short*)Cout)[(size_t)row * N + col] = f2bf(v);
        }
      }
    }
  }
}

// ---------------- MFMA attention -------------------------------------------
// grid (qtile=3, h=8, n=16), 256 threads = 4 waves; wave w owns Q rows
// q0 = qtile*64 + w*16. Full K [192][64] and V^T [64][192] in swizzled LDS.
// S = Q.K^T via mfma (A-frag: m=lane&15, k=(lane>>4)*8+j; verified m97 conv),
// exact softmax (C-layout: col=lane&15, row=(lane>>4)*4+r), P -> LDS bf16,
// O = P.V via mfma with B-frags from V^T.
__global__ __launch_bounds__(256) void attn_k(const unsigned short* __restrict__ qkv,
                                              unsigned short* __restrict__ o) {
  int qt = blockIdx.x, h = blockIdx.y, n = blockIdx.z;
  int t = threadIdx.x, lane = t & 63, w = t >> 6;
  __shared__ __align__(16) unsigned short Ks[192 * 64];   // swz: byte ^= (row&7)<<4, row stride 128B
  __shared__ __align__(16) unsigned short Vt[64 * 192];   // swz: byte ^= (row&7)<<4, row stride 384B
  __shared__ __align__(16) unsigned short Ps[4][16 * 192];// per-wave, same swizzle as Vt
  const unsigned short* base = qkv + (size_t)n * SEQ * 1536;

  // ---- stage K rows (coalesced global, conflict-free swizzled LDS write)
  #pragma unroll
  for (int i = 0; i < 6; ++i) {
    int idx = i * 256 + t;
    int row = idx >> 3, c8 = (idx & 7) << 3;
    short8v kv = *(const short8v*)(base + (size_t)row * 1536 + 512 + h * 64 + c8);
    int kb = (row * 128 + c8 * 2) ^ ((row & 7) << 4);
    *(short8v*)((char*)Ks + kb) = kv;
  }
  // ---- stage V transposed: idx -> (j = seq, d0): j varies fastest across a
  // wave so the 8 scalar LDS writes per thread spread banks (2-way max)
  #pragma unroll
  for (int i = 0; i < 6; ++i) {
    int idx = i * 256 + t;
    int j = (idx & 63) + ((idx >> 9) << 6);       // 0..191
    int d0 = ((idx >> 6) & 7) << 3;               // 0..56
    short8v vv = *(const short8v*)(base + (size_t)j * 1536 + 1024 + h * 64 + d0);
    #pragma unroll
    for (int e = 0; e < 8; ++e) {
      int d = d0 + e;
      int vb = (d * 384 + j * 2) ^ ((d & 7) << 4);
      *(unsigned short*)((char*)Vt + vb) = (unsigned short)vv[e];
    }
  }
  // ---- Q A-fragments for this wave's 16-row tile (direct from global)
  int q0 = qt * 64 + w * 16;
  const unsigned short* qp = base + (size_t)(q0 + (lane & 15)) * 1536 + h * 64 + ((lane >> 4) << 3);
  short8v aq0 = *(const short8v*)(qp);
  short8v aq1 = *(const short8v*)(qp + 32);
  __syncthreads();

  // ---- S = Q.K^T : 12 column tiles of 16 keys, K-dim 64 = 2 mfma steps
  f32x4 sa[12];
  #pragma unroll
  for (int ni = 0; ni < 12; ++ni) sa[ni] = (f32x4){0.f, 0.f, 0.f, 0.f};
  #pragma unroll
  for (int ks = 0; ks < 2; ++ks) {
    int kk = (ks << 5) + ((lane >> 4) << 3);
    short8v aq = ks ? aq1 : aq0;
    #pragma unroll
    for (int ni = 0; ni < 12; ++ni) {
      int krow = ni * 16 + (lane & 15);
      int kb = (krow * 128 + kk * 2) ^ ((krow & 7) << 4);
      short8v bk = *(const short8v*)((char*)Ks + kb);
      sa[ni] = __builtin_amdgcn_mfma_f32_16x16x32_bf16(aq, bk, sa[ni], 0, 0, 0);
    }
  }

  // ---- exact softmax over 192 keys; rows live at (lane>>4)*4 + r
  unsigned short* Pw = Ps[w];
  float l4[4];
  #pragma unroll
  for (int r = 0; r < 4; ++r) {
    float mx = sa[0][r];
    #pragma unroll
    for (int ni = 1; ni < 12; ++ni) mx = fmaxf(mx, sa[ni][r]);
    mx = fmaxf(mx, __shfl_xor(mx, 1, 64));
    mx = fmaxf(mx, __shfl_xor(mx, 2, 64));
    mx = fmaxf(mx, __shfl_xor(mx, 4, 64));
    mx = fmaxf(mx, __shfl_xor(mx, 8, 64));
    int prow = ((lane >> 4) << 2) + r;
    float sum = 0.f;
    #pragma unroll
    for (int ni = 0; ni < 12; ++ni) {
      float p = __expf((sa[ni][r] - mx) * 0.125f);   // fold SCALE here (exact)
      sum += p;
      int col = ni * 16 + (lane & 15);
      int pb = (prow * 384 + col * 2) ^ ((prow & 7) << 4);
      *(unsigned short*)((char*)Pw + pb) = f2bf(p);
    }
    sum += __shfl_xor(sum, 1, 64);
    sum += __shfl_xor(sum, 2, 64);
    sum += __shfl_xor(sum, 4, 64);
    sum += __shfl_xor(sum, 8, 64);
    l4[r] = sum;
  }

  // ---- O = P.V : A-frags from Pw, B-frags from Vt; K-dim 192 = 6 steps
  f32x4 oa[4];
  #pragma unroll
  for (int ni = 0; ni < 4; ++ni) oa[ni] = (f32x4){0.f, 0.f, 0.f, 0.f};
  #pragma unroll
  for (int ks = 0; ks < 6; ++ks) {
    int kk = (ks << 5) + ((lane >> 4) << 3);
    int m = lane & 15;
    int pb = (m * 384 + kk * 2) ^ ((m & 7) << 4);
    short8v pa = *(const short8v*)((char*)Pw + pb);
    #pragma unroll
    for (int ni = 0; ni < 4; ++ni) {
      int vrow = ni * 16 + (lane & 15);
      int vb = (vrow * 384 + kk * 2) ^ ((vrow & 7) << 4);
      short8v vbf = *(const short8v*)((char*)Vt + vb);
      oa[ni] = __builtin_amdgcn_mfma_f32_16x16x32_bf16(pa, vbf, oa[ni], 0, 0, 0);
    }
  }

  // ---- write O (bf16), divide by softmax denominator per row
  int rb = (lane >> 4) << 2;
  #pragma unroll
  for (int r = 0; r < 4; ++r) {
    float inv = 1.f / l4[r];
    unsigned short* dst = o + (size_t)(n * SEQ + q0 + rb + r) * 512 + h * 64 + (lane & 15);
    #pragma unroll
    for (int ni = 0; ni < 4; ++ni)
      dst[ni * 16] = f2bf(oa[ni][r] * inv);
  }
}

// ---------------------------------------------------------------------------
extern "C" void kernel_launch(void* const* d_in, const int* in_sizes, int n_in,
                              void* d_out, int out_size, void* d_ws, size_t ws_size,
                              hipStream_t stream) {
  const float* img   = (const float*)d_in[0];
  const float* ln1_g = (const float*)d_in[1];
  const float* ln1_b = (const float*)d_in[2];
  const float* wqkv  = (const float*)d_in[3];
  const float* wo    = (const float*)d_in[4];
  const float* bo    = (const float*)d_in[5];
  const float* ln2_g = (const float*)d_in[6];
  const float* ln2_b = (const float*)d_in[7];
  const float* w1    = (const float*)d_in[8];
  const float* b1    = (const float*)d_in[9];
  const float* w2    = (const float*)d_in[10];
  const float* b2    = (const float*)d_in[11];
  float* out = (float*)d_out;

  char* ws = (char*)d_ws;
  float*          x   = (float*)ws;                         // 12,582,912
  unsigned short* xn  = (unsigned short*)(ws + 12582912);   //  6,291,456
  unsigned short* big = (unsigned short*)(ws + 18874368);   // 12,582,912
  unsigned short* ob  = (unsigned short*)(ws + 31457280);   //  3,145,728
  unsigned short* wtb = (unsigned short*)(ws + 34603008);   // weight area

  // all-layers weight area needs 75,497,472 B -> total 110,100,480
  bool big_ws = (ws_size >= 110100480ull);
  size_t per_qkv = (size_t)1024 * 1536, per_o = (size_t)512 * 1024;
  size_t per_1   = (size_t)1024 * 2048, per_2 = (size_t)2048 * 1024;
  unsigned short *wt_qkv, *wt_o, *wt_1, *wt_2;
  if (big_ws) {
    wt_qkv = wtb;                     // 6 layers each
    wt_o   = wt_qkv + 6 * per_qkv;
    wt_1   = wt_o   + 6 * per_o;
    wt_2   = wt_1   + 6 * per_1;
    wconv_k<<<dim3(1536 / 32, 1024 / 32, 6), 256, 0, stream>>>(wqkv, wt_qkv, 1024, 1536);
    wconv_k<<<dim3(1024 / 32,  512 / 32, 6), 256, 0, stream>>>(wo,   wt_o,    512, 1024);
    wconv_k<<<dim3(2048 / 32, 1024 / 32, 6), 256, 0, stream>>>(w1,   wt_1,   1024, 2048);
    wconv_k<<<dim3(1024 / 32, 2048 / 32, 6), 256, 0, stream>>>(w2,   wt_2,   2048, 1024);
  } else {
    wt_qkv = wtb;
    wt_o   = wt_qkv + per_qkv;
    wt_1   = wt_o + per_o;
    wt_2   = wt_1 + per_1;
  }

  preproc_k<<<16384, 64, 0, stream>>>(img, x);

  for (int l = 0; l < 6; ++l) {
    unsigned short *wq_l, *wo_l, *w1_l, *w2_l;
    if (big_ws) {
      wq_l = wt_qkv + l * per_qkv; wo_l = wt_o + l * per_o;
      w1_l = wt_1 + l * per_1;     w2_l = wt_2 + l * per_2;
    } else {
      wconv_k<<<dim3(1536 / 32, 1024 / 32), 256, 0, stream>>>(wqkv + l * per_qkv, wt_qkv, 1024, 1536);
      wconv_k<<<dim3(1024 / 32,  512 / 32), 256, 0, stream>>>(wo   + l * per_o,   wt_o,    512, 1024);
      wconv_k<<<dim3(2048 / 32, 1024 / 32), 256, 0, stream>>>(w1   + l * per_1,   wt_1,   1024, 2048);
      wconv_k<<<dim3(1024 / 32, 2048 / 32), 256, 0, stream>>>(w2   + l * per_2,   wt_2,   2048, 1024);
      wq_l = wt_qkv; wo_l = wt_o; w1_l = wt_1; w2_l = wt_2;
    }

    ln_k<<<MROWS, 256, 0, stream>>>(x, ln1_g + l * 1024, ln1_b + l * 1024, xn);
    mm_k<0><<<dim3(12, 24), 256, 0, stream>>>(xn, wq_l, nullptr, nullptr, big, MROWS, 1536, 1024);
    attn_k<<<dim3(3, 8, 16), 256, 0, stream>>>(big, ob);
    mm_k<1><<<dim3(8, 24), 256, 0, stream>>>(ob, wo_l, bo + l * 1024, x, x, MROWS, 1024, 512);
    ln_k<<<MROWS, 256, 0, stream>>>(x, ln2_g + l * 1024, ln2_b + l * 1024, xn);
    mm_k<2><<<dim3(16, 24), 256, 0, stream>>>(xn, w1_l, b1 + l * 2048, nullptr, big, MROWS, 2048, 1024);
    mm_k<1><<<dim3(8, 24), 256, 0, stream>>>(big, w2_l, b2 + l * 1024, x, x, MROWS, 1024, 2048);
  }

  postproc_k<<<16384, 64, 0, stream>>>(x, out);
}

// Round 5
// 975.763 us; speedup vs baseline: 4.6314x; 1.1269x over previous
//
#include <hip/hip_runtime.h>
#include <math.h>

// ---------------------------------------------------------------------------
// JPEG-domain ViT. Round 5 (= round-4 design, compile-fixed): 8-wave in-block
// split-K GEMM. The round-4 failure was an array-of-LDS-pointers static
// initializer (addrspacecast) that gfx950 rejects; replaced with computed
// offsets off a single __shared__ base.
// ---------------------------------------------------------------------------

#define NIMG 16
#define SEQ 192
#define DIMV 1024
#define MROWS (NIMG * SEQ)   // 3072

typedef __attribute__((ext_vector_type(8))) short short8v;
typedef __attribute__((ext_vector_type(4))) float f32x4;
typedef unsigned int uint_t;

__device__ __forceinline__ unsigned short f2bf(float f) {
  union { float f; uint_t u; } x; x.f = f;
  uint_t r = x.u + 0x7fffu + ((x.u >> 16) & 1u);
  return (unsigned short)(r >> 16);
}

__device__ __forceinline__ void gload16(const void* g, void* l) {
  __builtin_amdgcn_global_load_lds(
      reinterpret_cast<const __attribute__((address_space(1))) void*>(
          reinterpret_cast<uintptr_t>(g)),
      reinterpret_cast<__attribute__((address_space(3))) void*>(
          reinterpret_cast<uintptr_t>(l)),
      16, 0, 0);
}

__constant__ float DCT8c[8][8] = {
  { 0.35355339f, 0.35355339f, 0.35355339f, 0.35355339f, 0.35355339f, 0.35355339f, 0.35355339f, 0.35355339f},
  { 0.49039264f, 0.41573481f, 0.27778512f, 0.09754516f,-0.09754516f,-0.27778512f,-0.41573481f,-0.49039264f},
  { 0.46193977f, 0.19134172f,-0.19134172f,-0.46193977f,-0.46193977f,-0.19134172f, 0.19134172f, 0.46193977f},
  { 0.41573481f,-0.09754516f,-0.49039264f,-0.27778512f, 0.27778512f, 0.49039264f, 0.09754516f,-0.41573481f},
  { 0.35355339f,-0.35355339f,-0.35355339f, 0.35355339f, 0.35355339f,-0.35355339f,-0.35355339f, 0.35355339f},
  { 0.27778512f,-0.49039264f, 0.09754516f, 0.41573481f,-0.41573481f,-0.09754516f, 0.49039264f,-0.27778512f},
  { 0.19134172f,-0.46193977f, 0.46193977f,-0.19134172f,-0.19134172f, 0.46193977f,-0.46193977f, 0.19134172f},
  { 0.09754516f,-0.27778512f, 0.41573481f,-0.49039264f, 0.49039264f,-0.41573481f, 0.27778512f,-0.09754516f}
};

// ---------------- preprocess: img -> tokens x[n, s=c*64+p*8+q, l=hb*32+wb] ----
__global__ void preproc_k(const float* __restrict__ img, float* __restrict__ x0) {
  int bid = blockIdx.x;
  int wb = bid & 31, hb = (bid >> 5) & 31, n = bid >> 10;
  int t = threadIdx.x, i = t >> 3, j = t & 7;
  __shared__ float blk[3][8][8];
  __shared__ float tmp[3][8][8];
  size_t pix = ((size_t)(n * 3) * 256 + hb * 8 + i) * 256 + wb * 8 + j;
  float r = img[pix], g = img[pix + 65536], b = img[pix + 131072];
  blk[0][i][j] =  0.299f   * r + 0.587f   * g + 0.114f   * b;
  blk[1][i][j] = -0.14713f * r - 0.28886f * g + 0.436f   * b;
  blk[2][i][j] =  0.615f   * r - 0.51499f * g - 0.10001f * b;
  __syncthreads();
  #pragma unroll
  for (int c = 0; c < 3; ++c) {
    float a = 0.f;
    #pragma unroll
    for (int k = 0; k < 8; ++k) a += DCT8c[i][k] * blk[c][k][j];
    tmp[c][i][j] = a;
  }
  __syncthreads();
  int l = hb * 32 + wb;
  #pragma unroll
  for (int c = 0; c < 3; ++c) {
    float a = 0.f;
    #pragma unroll
    for (int k = 0; k < 8; ++k) a += tmp[c][i][k] * DCT8c[j][k];
    float mk;
    if (c == 0) mk = ((i + j) <= 5 || ((i + j) == 6 && j < 4)) ? 1.f : 0.f;
    else        mk = ((i + j) <= 2 || ((i + j) == 3 && i < 3)) ? 1.f : 0.f;
    x0[((size_t)(n * SEQ + c * 64 + t)) * DIMV + l] = a * mk;
  }
}

// ---------------- postprocess: tokens -> rec = D*C*D^T -> YUV->RGB ----------
__global__ void postproc_k(const float* __restrict__ x, float* __restrict__ out) {
  int bid = blockIdx.x;
  int wb = bid & 31, hb = (bid >> 5) & 31, n = bid >> 10;
  int t = threadIdx.x, i = t >> 3, j = t & 7;
  __shared__ float cf[3][8][8];
  __shared__ float tmp[3][8][8];
  int l = hb * 32 + wb;
  #pragma unroll
  for (int c = 0; c < 3; ++c)
    cf[c][i][j] = x[((size_t)(n * SEQ + c * 64 + t)) * DIMV + l];
  __syncthreads();
  #pragma unroll
  for (int c = 0; c < 3; ++c) {
    float a = 0.f;
    #pragma unroll
    for (int k = 0; k < 8; ++k) a += DCT8c[i][k] * cf[c][k][j];
    tmp[c][i][j] = a;
  }
  __syncthreads();
  float a0 = 0.f, a1 = 0.f, a2 = 0.f;
  #pragma unroll
  for (int k = 0; k < 8; ++k) {
    a0 += tmp[0][i][k] * DCT8c[j][k];
    a1 += tmp[1][i][k] * DCT8c[j][k];
    a2 += tmp[2][i][k] * DCT8c[j][k];
  }
  size_t pix = ((size_t)(n * 3) * 256 + hb * 8 + i) * 256 + wb * 8 + j;
  out[pix]          = a0 + 1.13983f * a2;
  out[pix + 65536]  = a0 - 0.39465f * a1 - 0.5806f * a2;
  out[pix + 131072] = a0 + 2.03211f * a1;
}

// ---------------- weight transpose+convert: w[K][N] fp32 -> wt[N][K] bf16 ---
__global__ __launch_bounds__(256) void wconv_k(const float* __restrict__ w,
                                               unsigned short* __restrict__ wt,
                                               int K, int N) {
  size_t off = (size_t)blockIdx.z * K * N;
  w += off; wt += off;
  __shared__ float s[32][33];
  int t = threadIdx.x;
  int n0 = blockIdx.x << 5, k0 = blockIdx.y << 5;
  int r = t >> 3, c4 = (t & 7) << 2;
  float4 v = *(const float4*)(w + (size_t)(k0 + r) * N + n0 + c4);
  s[r][c4] = v.x; s[r][c4 + 1] = v.y; s[r][c4 + 2] = v.z; s[r][c4 + 3] = v.w;
  __syncthreads();
  ushort4 o;
  o.x = f2bf(s[c4 + 0][r]); o.y = f2bf(s[c4 + 1][r]);
  o.z = f2bf(s[c4 + 2][r]); o.w = f2bf(s[c4 + 3][r]);
  *(ushort4*)(wt + (size_t)(n0 + r) * K + k0 + c4) = o;
}

// ---------------- layernorm over last dim (1024): fp32 in -> bf16 out -------
__global__ __launch_bounds__(256) void ln_k(const float* __restrict__ x,
                                            const float* __restrict__ g,
                                            const float* __restrict__ b,
                                            unsigned short* __restrict__ out) {
  int row = blockIdx.x, t = threadIdx.x;
  float4 v = ((const float4*)(x + (size_t)row * DIMV))[t];
  float s  = v.x + v.y + v.z + v.w;
  float s2 = v.x * v.x + v.y * v.y + v.z * v.z + v.w * v.w;
  #pragma unroll
  for (int off = 32; off > 0; off >>= 1) {
    s  += __shfl_down(s,  off, 64);
    s2 += __shfl_down(s2, off, 64);
  }
  __shared__ float red[8];
  int w = t >> 6;
  if ((t & 63) == 0) { red[w] = s; red[4 + w] = s2; }
  __syncthreads();
  s  = red[0] + red[1] + red[2] + red[3];
  s2 = red[4] + red[5] + red[6] + red[7];
  float mu  = s * (1.f / 1024.f);
  float var = fmaxf(s2 * (1.f / 1024.f) - mu * mu, 0.f);
  float rs  = rsqrtf(var + 1e-5f);
  float4 gv = ((const float4*)g)[t];
  float4 bv = ((const float4*)b)[t];
  ushort4 ov;
  ov.x = f2bf((v.x - mu) * rs * gv.x + bv.x);
  ov.y = f2bf((v.y - mu) * rs * gv.y + bv.y);
  ov.z = f2bf((v.z - mu) * rs * gv.z + bv.z);
  ov.w = f2bf((v.w - mu) * rs * gv.w + bv.w);
  ((ushort4*)(out + (size_t)row * DIMV))[t] = ov;
}

// ---------------- bf16 MFMA GEMM, 8-wave in-block split-K -------------------
// C[M,N] = A[M,K] @ Bt[N,K]^T. 128x128 tile; wave w: quadrant q=w&3
// (64x64 out), K-half kh=w>>2. LDS layout (shorts):
//   smem[    0.. 4095] = A stage, K-half 0      (128 rows x 32)
//   smem[ 4096.. 8191] = A stage, K-half 1
//   smem[ 8192..12287] = B stage, K-half 0
//   smem[12288..16383] = B stage, K-half 1
// After the K loop, staging LDS is reused to reduce waves 4-7 into 0-3.
// EPI: 0 = plain->bf16, 1 = +bias+fp32 residual->fp32, 2 = +bias+GELU->bf16
template <int EPI>
__global__ __launch_bounds__(512) void mm_k(const unsigned short* __restrict__ A,
                                            const unsigned short* __restrict__ Bt,
                                            const float* __restrict__ bias,
                                            const float* res,
                                            void* Cout,
                                            int M, int N, int K) {
  __shared__ __align__(16) unsigned short smem[16384];

  int t = threadIdx.x;
  int lane = t & 63, w = t >> 6;         // 8 waves
  int kh = w >> 2;                        // K-half this wave computes
  int q  = w & 3;                         // output quadrant
  int m0 = blockIdx.y << 7, n0 = blockIdx.x << 7;
  int wm = (q >> 1) << 6, wn = (q & 1) << 6;
  int Kh = K >> 1;

  // staging: wave w stages rows w*16 .. w*16+15 (its 1KB slice) of each of
  // the 4 buffers. Lane l: row w*16 + (l>>2), elems (l&3)*8 .. +8.
  int srow = (w << 4) + (lane >> 2);
  int selem = (lane & 3) << 3;
  const unsigned short* Ag = A + (size_t)(m0 + srow) * K + selem;
  const unsigned short* Bg = Bt + (size_t)(n0 + srow) * K + selem;
  char* lA0 = (char*)smem + (w << 10);
  char* lA1 = lA0 + 8192;
  char* lB0 = lA0 + 16384;
  char* lB1 = lA0 + 24576;

  f32x4 acc[4][4] = {};

  const unsigned short* Aw = smem + kh * 4096;
  const unsigned short* Bw = smem + 8192 + kh * 4096;
  int fr_m = wm + (lane & 15);            // + mi*16, times 32 elems/row
  int fr_n = wn + (lane & 15);
  int fr_k = (lane >> 4) << 3;

  for (int k0 = 0; k0 < Kh; k0 += 32) {
    gload16(Ag + k0,      lA0);
    gload16(Ag + k0 + Kh, lA1);
    gload16(Bg + k0,      lB0);
    gload16(Bg + k0 + Kh, lB1);
    __syncthreads();
    short8v a[4], b[4];
    #pragma unroll
    for (int mi = 0; mi < 4; ++mi)
      a[mi] = *(const short8v*)&Aw[(fr_m + mi * 16) * 32 + fr_k];
    #pragma unroll
    for (int ni = 0; ni < 4; ++ni)
      b[ni] = *(const short8v*)&Bw[(fr_n + ni * 16) * 32 + fr_k];
    #pragma unroll
    for (int mi = 0; mi < 4; ++mi)
      #pragma unroll
      for (int ni = 0; ni < 4; ++ni)
        acc[mi][ni] = __builtin_amdgcn_mfma_f32_16x16x32_bf16(a[mi], b[ni], acc[mi][ni], 0, 0, 0);
    __syncthreads();
  }

  // ---- reduce waves 4-7 into waves 0-3 (staging LDS is dead now) ----------
  // chunk c covers acc[2c..2c+1][0..3] = 8 f32x4/lane; slice (w-4)*8+r, 1KB ea
  #pragma unroll
  for (int c = 0; c < 2; ++c) {
    if (w >= 4) {
      #pragma unroll
      for (int r = 0; r < 8; ++r)
        *(f32x4*)((char*)smem + (((w - 4) * 8 + r) << 10) + (lane << 4)) =
            acc[2 * c + (r >> 2)][r & 3];
    }
    __syncthreads();
    if (w < 4) {
      #pragma unroll
      for (int r = 0; r < 8; ++r) {
        f32x4 v = *(const f32x4*)((char*)smem + ((w * 8 + r) << 10) + (lane << 4));
        acc[2 * c + (r >> 2)][r & 3] += v;
      }
    }
    __syncthreads();
  }

  if (w >= 4) return;

  // epilogue: C/D frag layout col = lane&15, row = (lane>>4)*4 + r  [m89/m91]
  int cn = lane & 15;
  int rb = (lane >> 4) << 2;
  #pragma unroll
  for (int mi = 0; mi < 4; ++mi) {
    #pragma unroll
    for (int ni = 0; ni < 4; ++ni) {
      int col = n0 + wn + ni * 16 + cn;
      #pragma unroll
      for (int r = 0; r < 4; ++r) {
        int row = m0 + wm + mi * 16 + rb + r;
        float v = acc[mi][ni][r];
        if (EPI >= 1) v += bias[col];
        if (EPI == 1) {
          ((float*)Cout)[(size_t)row * N + col] = v + res[(size_t)row * N + col];
        } else if (EPI == 2) {
          v = 0.5f * v * (1.f + erff(v * 0.70710678f));
          ((unsigned short*)Cout)[(size_t)row * N + col] = f2bf(v);
        } else {
          ((unsigned short*)Cout)[(size_t)row * N + col] = f2bf(v);
        }
      }
    }
  }
}

// ---------------- MFMA attention (round 3, unchanged) -----------------------
__global__ __launch_bounds__(256) void attn_k(const unsigned short* __restrict__ qkv,
                                              unsigned short* __restrict__ o) {
  int qt = blockIdx.x, h = blockIdx.y, n = blockIdx.z;
  int t = threadIdx.x, lane = t & 63, w = t >> 6;
  __shared__ __align__(16) unsigned short Ks[192 * 64];
  __shared__ __align__(16) unsigned short Vt[64 * 192];
  __shared__ __align__(16) unsigned short Ps[4][16 * 192];
  const unsigned short* base = qkv + (size_t)n * SEQ * 1536;

  #pragma unroll
  for (int i = 0; i < 6; ++i) {
    int idx = i * 256 + t;
    int row = idx >> 3, c8 = (idx & 7) << 3;
    short8v kv = *(const short8v*)(base + (size_t)row * 1536 + 512 + h * 64 + c8);
    int kb = (row * 128 + c8 * 2) ^ ((row & 7) << 4);
    *(short8v*)((char*)Ks + kb) = kv;
  }
  #pragma unroll
  for (int i = 0; i < 6; ++i) {
    int idx = i * 256 + t;
    int j = (idx & 63) + ((idx >> 9) << 6);
    int d0 = ((idx >> 6) & 7) << 3;
    short8v vv = *(const short8v*)(base + (size_t)j * 1536 + 1024 + h * 64 + d0);
    #pragma unroll
    for (int e = 0; e < 8; ++e) {
      int d = d0 + e;
      int vb = (d * 384 + j * 2) ^ ((d & 7) << 4);
      *(unsigned short*)((char*)Vt + vb) = (unsigned short)vv[e];
    }
  }
  int q0 = qt * 64 + w * 16;
  const unsigned short* qp = base + (size_t)(q0 + (lane & 15)) * 1536 + h * 64 + ((lane >> 4) << 3);
  short8v aq0 = *(const short8v*)(qp);
  short8v aq1 = *(const short8v*)(qp + 32);
  __syncthreads();

  f32x4 sa[12];
  #pragma unroll
  for (int ni = 0; ni < 12; ++ni) sa[ni] = (f32x4){0.f, 0.f, 0.f, 0.f};
  #pragma unroll
  for (int ks = 0; ks < 2; ++ks) {
    int kk = (ks << 5) + ((lane >> 4) << 3);
    short8v aq = ks ? aq1 : aq0;
    #pragma unroll
    for (int ni = 0; ni < 12; ++ni) {
      int krow = ni * 16 + (lane & 15);
      int kb = (krow * 128 + kk * 2) ^ ((krow & 7) << 4);
      short8v bk = *(const short8v*)((char*)Ks + kb);
      sa[ni] = __builtin_amdgcn_mfma_f32_16x16x32_bf16(aq, bk, sa[ni], 0, 0, 0);
    }
  }

  unsigned short* Pw = Ps[w];
  float l4[4];
  #pragma unroll
  for (int r = 0; r < 4; ++r) {
    float mx = sa[0][r];
    #pragma unroll
    for (int ni = 1; ni < 12; ++ni) mx = fmaxf(mx, sa[ni][r]);
    mx = fmaxf(mx, __shfl_xor(mx, 1, 64));
    mx = fmaxf(mx, __shfl_xor(mx, 2, 64));
    mx = fmaxf(mx, __shfl_xor(mx, 4, 64));
    mx = fmaxf(mx, __shfl_xor(mx, 8, 64));
    int prow = ((lane >> 4) << 2) + r;
    float sum = 0.f;
    #pragma unroll
    for (int ni = 0; ni < 12; ++ni) {
      float p = __expf((sa[ni][r] - mx) * 0.125f);
      sum += p;
      int col = ni * 16 + (lane & 15);
      int pb = (prow * 384 + col * 2) ^ ((prow & 7) << 4);
      *(unsigned short*)((char*)Pw + pb) = f2bf(p);
    }
    sum += __shfl_xor(sum, 1, 64);
    sum += __shfl_xor(sum, 2, 64);
    sum += __shfl_xor(sum, 4, 64);
    sum += __shfl_xor(sum, 8, 64);
    l4[r] = sum;
  }

  f32x4 oa[4];
  #pragma unroll
  for (int ni = 0; ni < 4; ++ni) oa[ni] = (f32x4){0.f, 0.f, 0.f, 0.f};
  #pragma unroll
  for (int ks = 0; ks < 6; ++ks) {
    int kk = (ks << 5) + ((lane >> 4) << 3);
    int m = lane & 15;
    int pb = (m * 384 + kk * 2) ^ ((m & 7) << 4);
    short8v pa = *(const short8v*)((char*)Pw + pb);
    #pragma unroll
    for (int ni = 0; ni < 4; ++ni) {
      int vrow = ni * 16 + (lane & 15);
      int vb = (vrow * 384 + kk * 2) ^ ((vrow & 7) << 4);
      short8v vbf = *(const short8v*)((char*)Vt + vb);
      oa[ni] = __builtin_amdgcn_mfma_f32_16x16x32_bf16(pa, vbf, oa[ni], 0, 0, 0);
    }
  }

  int rb = (lane >> 4) << 2;
  #pragma unroll
  for (int r = 0; r < 4; ++r) {
    float inv = 1.f / l4[r];
    unsigned short* dst = o + (size_t)(n * SEQ + q0 + rb + r) * 512 + h * 64 + (lane & 15);
    #pragma unroll
    for (int ni = 0; ni < 4; ++ni)
      dst[ni * 16] = f2bf(oa[ni][r] * inv);
  }
}

// ---------------------------------------------------------------------------
extern "C" void kernel_launch(void* const* d_in, const int* in_sizes, int n_in,
                              void* d_out, int out_size, void* d_ws, size_t ws_size,
                              hipStream_t stream) {
  const float* img   = (const float*)d_in[0];
  const float* ln1_g = (const float*)d_in[1];
  const float* ln1_b = (const float*)d_in[2];
  const float* wqkv  = (const float*)d_in[3];
  const float* wo    = (const float*)d_in[4];
  const float* bo    = (const float*)d_in[5];
  const float* ln2_g = (const float*)d_in[6];
  const float* ln2_b = (const float*)d_in[7];
  const float* w1    = (const float*)d_in[8];
  const float* b1    = (const float*)d_in[9];
  const float* w2    = (const float*)d_in[10];
  const float* b2    = (const float*)d_in[11];
  float* out = (float*)d_out;

  char* ws = (char*)d_ws;
  float*          x   = (float*)ws;                         // 12,582,912
  unsigned short* xn  = (unsigned short*)(ws + 12582912);   //  6,291,456
  unsigned short* big = (unsigned short*)(ws + 18874368);   // 12,582,912
  unsigned short* ob  = (unsigned short*)(ws + 31457280);   //  3,145,728
  unsigned short* wtb = (unsigned short*)(ws + 34603008);   // weight area

  bool big_ws = (ws_size >= 110100480ull);
  size_t per_qkv = (size_t)1024 * 1536, per_o = (size_t)512 * 1024;
  size_t per_1   = (size_t)1024 * 2048, per_2 = (size_t)2048 * 1024;
  unsigned short *wt_qkv, *wt_o, *wt_1, *wt_2;
  if (big_ws) {
    wt_qkv = wtb;
    wt_o   = wt_qkv + 6 * per_qkv;
    wt_1   = wt_o   + 6 * per_o;
    wt_2   = wt_1   + 6 * per_1;
    wconv_k<<<dim3(1536 / 32, 1024 / 32, 6), 256, 0, stream>>>(wqkv, wt_qkv, 1024, 1536);
    wconv_k<<<dim3(1024 / 32,  512 / 32, 6), 256, 0, stream>>>(wo,   wt_o,    512, 1024);
    wconv_k<<<dim3(2048 / 32, 1024 / 32, 6), 256, 0, stream>>>(w1,   wt_1,   1024, 2048);
    wconv_k<<<dim3(1024 / 32, 2048 / 32, 6), 256, 0, stream>>>(w2,   wt_2,   2048, 1024);
  } else {
    wt_qkv = wtb;
    wt_o   = wt_qkv + per_qkv;
    wt_1   = wt_o + per_o;
    wt_2   = wt_1 + per_1;
  }

  preproc_k<<<16384, 64, 0, stream>>>(img, x);

  for (int l = 0; l < 6; ++l) {
    unsigned short *wq_l, *wo_l, *w1_l, *w2_l;
    if (big_ws) {
      wq_l = wt_qkv + l * per_qkv; wo_l = wt_o + l * per_o;
      w1_l = wt_1 + l * per_1;     w2_l = wt_2 + l * per_2;
    } else {
      wconv_k<<<dim3(1536 / 32, 1024 / 32), 256, 0, stream>>>(wqkv + l * per_qkv, wt_qkv, 1024, 1536);
      wconv_k<<<dim3(1024 / 32,  512 / 32), 256, 0, stream>>>(wo   + l * per_o,   wt_o,    512, 1024);
      wconv_k<<<dim3(2048 / 32, 1024 / 32), 256, 0, stream>>>(w1   + l * per_1,   wt_1,   1024, 2048);
      wconv_k<<<dim3(1024 / 32, 2048 / 32), 256, 0, stream>>>(w2   + l * per_2,   wt_2,   2048, 1024);
      wq_l = wt_qkv; wo_l = wt_o; w1_l = wt_1; w2_l = wt_2;
    }

    ln_k<<<MROWS, 256, 0, stream>>>(x, ln1_g + l * 1024, ln1_b + l * 1024, xn);
    mm_k<0><<<dim3(12, 24), 512, 0, stream>>>(xn, wq_l, nullptr, nullptr, big, MROWS, 1536, 1024);
    attn_k<<<dim3(3, 8, 16), 256, 0, stream>>>(big, ob);
    mm_k<1><<<dim3(8, 24), 512, 0, stream>>>(ob, wo_l, bo + l * 1024, x, x, MROWS, 1024, 512);
    ln_k<<<MROWS, 256, 0, stream>>>(x, ln2_g + l * 1024, ln2_b + l * 1024, xn);
    mm_k<2><<<dim3(16, 24), 512, 0, stream>>>(xn, w1_l, b1 + l * 2048, nullptr, big, MROWS, 2048, 1024);
    mm_k<1><<<dim3(8, 24), 512, 0, stream>>>(big, w2_l, b2 + l * 1024, x, x, MROWS, 1024, 2048);
  }

  postproc_k<<<16384, 64, 0, stream>>>(x, out);
}

// Round 6
// 864.250 us; speedup vs baseline: 5.2290x; 1.1290x over previous
//
#include <hip/hip_runtime.h>
#include <math.h>

// ---------------------------------------------------------------------------
// JPEG-domain ViT. Round 6: GEMM = 8-wave split-K + double-buffered 2-phase
// pipeline (issue next-tile global_load_lds BEFORE current-tile compute; one
// barrier per K-step hides stage latency under ds_read+MFMA). Tile 128x64 so
// all grids are 384-768 blocks (w1: 768 = exactly 3 blocks/CU, balanced).
// ---------------------------------------------------------------------------

#define NIMG 16
#define SEQ 192
#define DIMV 1024
#define MROWS (NIMG * SEQ)   // 3072

typedef __attribute__((ext_vector_type(8))) short short8v;
typedef __attribute__((ext_vector_type(4))) float f32x4;
typedef unsigned int uint_t;

__device__ __forceinline__ unsigned short f2bf(float f) {
  union { float f; uint_t u; } x; x.f = f;
  uint_t r = x.u + 0x7fffu + ((x.u >> 16) & 1u);
  return (unsigned short)(r >> 16);
}

__device__ __forceinline__ void gload16(const void* g, void* l) {
  __builtin_amdgcn_global_load_lds(
      reinterpret_cast<const __attribute__((address_space(1))) void*>(
          reinterpret_cast<uintptr_t>(g)),
      reinterpret_cast<__attribute__((address_space(3))) void*>(
          reinterpret_cast<uintptr_t>(l)),
      16, 0, 0);
}

__constant__ float DCT8c[8][8] = {
  { 0.35355339f, 0.35355339f, 0.35355339f, 0.35355339f, 0.35355339f, 0.35355339f, 0.35355339f, 0.35355339f},
  { 0.49039264f, 0.41573481f, 0.27778512f, 0.09754516f,-0.09754516f,-0.27778512f,-0.41573481f,-0.49039264f},
  { 0.46193977f, 0.19134172f,-0.19134172f,-0.46193977f,-0.46193977f,-0.19134172f, 0.19134172f, 0.46193977f},
  { 0.41573481f,-0.09754516f,-0.49039264f,-0.27778512f, 0.27778512f, 0.49039264f, 0.09754516f,-0.41573481f},
  { 0.35355339f,-0.35355339f,-0.35355339f, 0.35355339f, 0.35355339f,-0.35355339f,-0.35355339f, 0.35355339f},
  { 0.27778512f,-0.49039264f, 0.09754516f, 0.41573481f,-0.41573481f,-0.09754516f, 0.49039264f,-0.27778512f},
  { 0.19134172f,-0.46193977f, 0.46193977f,-0.19134172f,-0.19134172f, 0.46193977f,-0.46193977f, 0.19134172f},
  { 0.09754516f,-0.27778512f, 0.41573481f,-0.49039264f, 0.49039264f,-0.41573481f, 0.27778512f,-0.09754516f}
};

// ---------------- preprocess: img -> tokens x[n, s=c*64+p*8+q, l=hb*32+wb] ----
__global__ void preproc_k(const float* __restrict__ img, float* __restrict__ x0) {
  int bid = blockIdx.x;
  int wb = bid & 31, hb = (bid >> 5) & 31, n = bid >> 10;
  int t = threadIdx.x, i = t >> 3, j = t & 7;
  __shared__ float blk[3][8][8];
  __shared__ float tmp[3][8][8];
  size_t pix = ((size_t)(n * 3) * 256 + hb * 8 + i) * 256 + wb * 8 + j;
  float r = img[pix], g = img[pix + 65536], b = img[pix + 131072];
  blk[0][i][j] =  0.299f   * r + 0.587f   * g + 0.114f   * b;
  blk[1][i][j] = -0.14713f * r - 0.28886f * g + 0.436f   * b;
  blk[2][i][j] =  0.615f   * r - 0.51499f * g - 0.10001f * b;
  __syncthreads();
  #pragma unroll
  for (int c = 0; c < 3; ++c) {
    float a = 0.f;
    #pragma unroll
    for (int k = 0; k < 8; ++k) a += DCT8c[i][k] * blk[c][k][j];
    tmp[c][i][j] = a;
  }
  __syncthreads();
  int l = hb * 32 + wb;
  #pragma unroll
  for (int c = 0; c < 3; ++c) {
    float a = 0.f;
    #pragma unroll
    for (int k = 0; k < 8; ++k) a += tmp[c][i][k] * DCT8c[j][k];
    float mk;
    if (c == 0) mk = ((i + j) <= 5 || ((i + j) == 6 && j < 4)) ? 1.f : 0.f;
    else        mk = ((i + j) <= 2 || ((i + j) == 3 && i < 3)) ? 1.f : 0.f;
    x0[((size_t)(n * SEQ + c * 64 + t)) * DIMV + l] = a * mk;
  }
}

// ---------------- postprocess: tokens -> rec = D*C*D^T -> YUV->RGB ----------
__global__ void postproc_k(const float* __restrict__ x, float* __restrict__ out) {
  int bid = blockIdx.x;
  int wb = bid & 31, hb = (bid >> 5) & 31, n = bid >> 10;
  int t = threadIdx.x, i = t >> 3, j = t & 7;
  __shared__ float cf[3][8][8];
  __shared__ float tmp[3][8][8];
  int l = hb * 32 + wb;
  #pragma unroll
  for (int c = 0; c < 3; ++c)
    cf[c][i][j] = x[((size_t)(n * SEQ + c * 64 + t)) * DIMV + l];
  __syncthreads();
  #pragma unroll
  for (int c = 0; c < 3; ++c) {
    float a = 0.f;
    #pragma unroll
    for (int k = 0; k < 8; ++k) a += DCT8c[i][k] * cf[c][k][j];
    tmp[c][i][j] = a;
  }
  __syncthreads();
  float a0 = 0.f, a1 = 0.f, a2 = 0.f;
  #pragma unroll
  for (int k = 0; k < 8; ++k) {
    a0 += tmp[0][i][k] * DCT8c[j][k];
    a1 += tmp[1][i][k] * DCT8c[j][k];
    a2 += tmp[2][i][k] * DCT8c[j][k];
  }
  size_t pix = ((size_t)(n * 3) * 256 + hb * 8 + i) * 256 + wb * 8 + j;
  out[pix]          = a0 + 1.13983f * a2;
  out[pix + 65536]  = a0 - 0.39465f * a1 - 0.5806f * a2;
  out[pix + 131072] = a0 + 2.03211f * a1;
}

// ---------------- weight transpose+convert: w[K][N] fp32 -> wt[N][K] bf16 ---
__global__ __launch_bounds__(256) void wconv_k(const float* __restrict__ w,
                                               unsigned short* __restrict__ wt,
                                               int K, int N) {
  size_t off = (size_t)blockIdx.z * K * N;
  w += off; wt += off;
  __shared__ float s[32][33];
  int t = threadIdx.x;
  int n0 = blockIdx.x << 5, k0 = blockIdx.y << 5;
  int r = t >> 3, c4 = (t & 7) << 2;
  float4 v = *(const float4*)(w + (size_t)(k0 + r) * N + n0 + c4);
  s[r][c4] = v.x; s[r][c4 + 1] = v.y; s[r][c4 + 2] = v.z; s[r][c4 + 3] = v.w;
  __syncthreads();
  ushort4 o;
  o.x = f2bf(s[c4 + 0][r]); o.y = f2bf(s[c4 + 1][r]);
  o.z = f2bf(s[c4 + 2][r]); o.w = f2bf(s[c4 + 3][r]);
  *(ushort4*)(wt + (size_t)(n0 + r) * K + k0 + c4) = o;
}

// ---------------- layernorm over last dim (1024): fp32 in -> bf16 out -------
__global__ __launch_bounds__(256) void ln_k(const float* __restrict__ x,
                                            const float* __restrict__ g,
                                            const float* __restrict__ b,
                                            unsigned short* __restrict__ out) {
  int row = blockIdx.x, t = threadIdx.x;
  float4 v = ((const float4*)(x + (size_t)row * DIMV))[t];
  float s  = v.x + v.y + v.z + v.w;
  float s2 = v.x * v.x + v.y * v.y + v.z * v.z + v.w * v.w;
  #pragma unroll
  for (int off = 32; off > 0; off >>= 1) {
    s  += __shfl_down(s,  off, 64);
    s2 += __shfl_down(s2, off, 64);
  }
  __shared__ float red[8];
  int w = t >> 6;
  if ((t & 63) == 0) { red[w] = s; red[4 + w] = s2; }
  __syncthreads();
  s  = red[0] + red[1] + red[2] + red[3];
  s2 = red[4] + red[5] + red[6] + red[7];
  float mu  = s * (1.f / 1024.f);
  float var = fmaxf(s2 * (1.f / 1024.f) - mu * mu, 0.f);
  float rs  = rsqrtf(var + 1e-5f);
  float4 gv = ((const float4*)g)[t];
  float4 bv = ((const float4*)b)[t];
  ushort4 ov;
  ov.x = f2bf((v.x - mu) * rs * gv.x + bv.x);
  ov.y = f2bf((v.y - mu) * rs * gv.y + bv.y);
  ov.z = f2bf((v.z - mu) * rs * gv.z + bv.z);
  ov.w = f2bf((v.w - mu) * rs * gv.w + bv.w);
  ((ushort4*)(out + (size_t)row * DIMV))[t] = ov;
}

// ---------------- bf16 MFMA GEMM: 128x64 tile, 8-wave split-K, dbuf pipeline
// C[M,N] = A[M,K] @ Bt[N,K]^T. Wave w: quadrant q=w&3 -> (wm = (q>>1)*64,
// wn = (q&1)*32), K-half kh=w>>2. Per K-step (64 cols = 32/half):
//   issue next-tile global_load_lds (3/thread) -> ds_read+MFMA current ->
//   one __syncthreads() (drains vmcnt for the in-flight next tile under the
//   compute we just did).
// LDS (shorts): A[db][half] = db*8192 + half*4096   (128 rows x 32)
//               B[db][half] = 16384 + db*4096 + half*2048 (64 rows x 32)
// Total 24576 shorts = 48 KB -> 3 blocks/CU. Reduction reuses smem (16 KB).
// EPI: 0 = plain->bf16, 1 = +bias+fp32 residual->fp32, 2 = +bias+GELU->bf16
template <int EPI>
__global__ __launch_bounds__(512) void mm_k(const unsigned short* __restrict__ A,
                                            const unsigned short* __restrict__ Bt,
                                            const float* __restrict__ bias,
                                            const float* res,
                                            void* Cout,
                                            int M, int N, int K) {
  __shared__ __align__(16) unsigned short smem[24576];

  int t = threadIdx.x;
  int lane = t & 63, w = t >> 6;         // 8 waves
  int kh = w >> 2;                        // K-half this wave computes
  int q  = w & 3;                         // output quadrant
  int m0 = blockIdx.y << 7, n0 = blockIdx.x << 6;
  int wm = (q >> 1) << 6, wn = (q & 1) << 5;
  int Kh = K >> 1;

  // staging addresses
  int arow = (w << 4) + (lane >> 2);           // 0..127
  int brow = ((w & 3) << 4) + (lane >> 2);     // 0..63
  int selem = (lane & 3) << 3;
  const unsigned short* Ag = A + (size_t)(m0 + arow) * K + selem;
  const unsigned short* Bg = Bt + (size_t)(n0 + brow) * K + ((w >> 2) ? Kh : 0) + selem;
  char* smb = (char*)smem;

  f32x4 acc[4][2] = {};

  // fragment read offsets (verified m97 convention)
  int fr_m = wm + (lane & 15);
  int fr_n = wn + (lane & 15);
  int fr_k = (lane >> 4) << 3;

  int nt = Kh >> 5;
  // prologue: stage tile 0 into db=0
  gload16(Ag,      smb + (w << 10));
  gload16(Ag + Kh, smb + 8192 + (w << 10));
  gload16(Bg,      smb + 32768 + ((w >> 2) << 12) + ((w & 3) << 10));
  __syncthreads();

  int db = 0;
  for (int it = 0; it < nt; ++it) {
    if (it + 1 < nt) {                       // issue next tile into db^1
      int k0 = (it + 1) << 5;
      int dbo = (db ^ 1);
      gload16(Ag + k0,      smb + dbo * 16384 + (w << 10));
      gload16(Ag + k0 + Kh, smb + dbo * 16384 + 8192 + (w << 10));
      gload16(Bg + k0,      smb + 32768 + dbo * 8192 + ((w >> 2) << 12) + ((w & 3) << 10));
    }
    // compute on db
    const unsigned short* Aw = smem + db * 8192 + kh * 4096;
    const unsigned short* Bw = smem + 16384 + db * 4096 + kh * 2048;
    short8v a[4], b[2];
    #pragma unroll
    for (int mi = 0; mi < 4; ++mi)
      a[mi] = *(const short8v*)&Aw[(fr_m + mi * 16) * 32 + fr_k];
    #pragma unroll
    for (int ni = 0; ni < 2; ++ni)
      b[ni] = *(const short8v*)&Bw[(fr_n + ni * 16) * 32 + fr_k];
    #pragma unroll
    for (int mi = 0; mi < 4; ++mi)
      #pragma unroll
      for (int ni = 0; ni < 2; ++ni)
        acc[mi][ni] = __builtin_amdgcn_mfma_f32_16x16x32_bf16(a[mi], b[ni], acc[mi][ni], 0, 0, 0);
    __syncthreads();   // drains lds-reads + the in-flight next-tile loads
    db ^= 1;
  }

  // ---- reduce waves 4-7 into waves 0-3 (16 KB chunks in dead staging LDS) --
  #pragma unroll
  for (int c = 0; c < 2; ++c) {
    if (w >= 4) {
      #pragma unroll
      for (int r = 0; r < 4; ++r)
        *(f32x4*)(smb + (((w - 4) * 4 + r) << 10) + (lane << 4)) =
            acc[2 * c + (r >> 1)][r & 1];
    }
    __syncthreads();
    if (w < 4) {
      #pragma unroll
      for (int r = 0; r < 4; ++r)
        acc[2 * c + (r >> 1)][r & 1] +=
            *(const f32x4*)(smb + ((w * 4 + r) << 10) + (lane << 4));
    }
    __syncthreads();
  }

  if (w >= 4) return;

  // epilogue: C/D frag layout col = lane&15, row = (lane>>4)*4 + r  [m89/m91]
  int cn = lane & 15;
  int rb = (lane >> 4) << 2;
  #pragma unroll
  for (int mi = 0; mi < 4; ++mi) {
    #pragma unroll
    for (int ni = 0; ni < 2; ++ni) {
      int col = n0 + wn + ni * 16 + cn;
      #pragma unroll
      for (int r = 0; r < 4; ++r) {
        int row = m0 + wm + mi * 16 + rb + r;
        float v = acc[mi][ni][r];
        if (EPI >= 1) v += bias[col];
        if (EPI == 1) {
          ((float*)Cout)[(size_t)row * N + col] = v + res[(size_t)row * N + col];
        } else if (EPI == 2) {
          v = 0.5f * v * (1.f + erff(v * 0.70710678f));
          ((unsigned short*)Cout)[(size_t)row * N + col] = f2bf(v);
        } else {
          ((unsigned short*)Cout)[(size_t)row * N + col] = f2bf(v);
        }
      }
    }
  }
}

// ---------------- MFMA attention (round 3, unchanged) -----------------------
__global__ __launch_bounds__(256) void attn_k(const unsigned short* __restrict__ qkv,
                                              unsigned short* __restrict__ o) {
  int qt = blockIdx.x, h = blockIdx.y, n = blockIdx.z;
  int t = threadIdx.x, lane = t & 63, w = t >> 6;
  __shared__ __align__(16) unsigned short Ks[192 * 64];
  __shared__ __align__(16) unsigned short Vt[64 * 192];
  __shared__ __align__(16) unsigned short Ps[4][16 * 192];
  const unsigned short* base = qkv + (size_t)n * SEQ * 1536;

  #pragma unroll
  for (int i = 0; i < 6; ++i) {
    int idx = i * 256 + t;
    int row = idx >> 3, c8 = (idx & 7) << 3;
    short8v kv = *(const short8v*)(base + (size_t)row * 1536 + 512 + h * 64 + c8);
    int kb = (row * 128 + c8 * 2) ^ ((row & 7) << 4);
    *(short8v*)((char*)Ks + kb) = kv;
  }
  #pragma unroll
  for (int i = 0; i < 6; ++i) {
    int idx = i * 256 + t;
    int j = (idx & 63) + ((idx >> 9) << 6);
    int d0 = ((idx >> 6) & 7) << 3;
    short8v vv = *(const short8v*)(base + (size_t)j * 1536 + 1024 + h * 64 + d0);
    #pragma unroll
    for (int e = 0; e < 8; ++e) {
      int d = d0 + e;
      int vb = (d * 384 + j * 2) ^ ((d & 7) << 4);
      *(unsigned short*)((char*)Vt + vb) = (unsigned short)vv[e];
    }
  }
  int q0 = qt * 64 + w * 16;
  const unsigned short* qp = base + (size_t)(q0 + (lane & 15)) * 1536 + h * 64 + ((lane >> 4) << 3);
  short8v aq0 = *(const short8v*)(qp);
  short8v aq1 = *(const short8v*)(qp + 32);
  __syncthreads();

  f32x4 sa[12];
  #pragma unroll
  for (int ni = 0; ni < 12; ++ni) sa[ni] = (f32x4){0.f, 0.f, 0.f, 0.f};
  #pragma unroll
  for (int ks = 0; ks < 2; ++ks) {
    int kk = (ks << 5) + ((lane >> 4) << 3);
    short8v aq = ks ? aq1 : aq0;
    #pragma unroll
    for (int ni = 0; ni < 12; ++ni) {
      int krow = ni * 16 + (lane & 15);
      int kb = (krow * 128 + kk * 2) ^ ((krow & 7) << 4);
      short8v bk = *(const short8v*)((char*)Ks + kb);
      sa[ni] = __builtin_amdgcn_mfma_f32_16x16x32_bf16(aq, bk, sa[ni], 0, 0, 0);
    }
  }

  unsigned short* Pw = Ps[w];
  float l4[4];
  #pragma unroll
  for (int r = 0; r < 4; ++r) {
    float mx = sa[0][r];
    #pragma unroll
    for (int ni = 1; ni < 12; ++ni) mx = fmaxf(mx, sa[ni][r]);
    mx = fmaxf(mx, __shfl_xor(mx, 1, 64));
    mx = fmaxf(mx, __shfl_xor(mx, 2, 64));
    mx = fmaxf(mx, __shfl_xor(mx, 4, 64));
    mx = fmaxf(mx, __shfl_xor(mx, 8, 64));
    int prow = ((lane >> 4) << 2) + r;
    float sum = 0.f;
    #pragma unroll
    for (int ni = 0; ni < 12; ++ni) {
      float p = __expf((sa[ni][r] - mx) * 0.125f);
      sum += p;
      int col = ni * 16 + (lane & 15);
      int pb = (prow * 384 + col * 2) ^ ((prow & 7) << 4);
      *(unsigned short*)((char*)Pw + pb) = f2bf(p);
    }
    sum += __shfl_xor(sum, 1, 64);
    sum += __shfl_xor(sum, 2, 64);
    sum += __shfl_xor(sum, 4, 64);
    sum += __shfl_xor(sum, 8, 64);
    l4[r] = sum;
  }

  f32x4 oa[4];
  #pragma unroll
  for (int ni = 0; ni < 4; ++ni) oa[ni] = (f32x4){0.f, 0.f, 0.f, 0.f};
  #pragma unroll
  for (int ks = 0; ks < 6; ++ks) {
    int kk = (ks << 5) + ((lane >> 4) << 3);
    int m = lane & 15;
    int pb = (m * 384 + kk * 2) ^ ((m & 7) << 4);
    short8v pa = *(const short8v*)((char*)Pw + pb);
    #pragma unroll
    for (int ni = 0; ni < 4; ++ni) {
      int vrow = ni * 16 + (lane & 15);
      int vb = (vrow * 384 + kk * 2) ^ ((vrow & 7) << 4);
      short8v vbf = *(const short8v*)((char*)Vt + vb);
      oa[ni] = __builtin_amdgcn_mfma_f32_16x16x32_bf16(pa, vbf, oa[ni], 0, 0, 0);
    }
  }

  int rb = (lane >> 4) << 2;
  #pragma unroll
  for (int r = 0; r < 4; ++r) {
    float inv = 1.f / l4[r];
    unsigned short* dst = o + (size_t)(n * SEQ + q0 + rb + r) * 512 + h * 64 + (lane & 15);
    #pragma unroll
    for (int ni = 0; ni < 4; ++ni)
      dst[ni * 16] = f2bf(oa[ni][r] * inv);
  }
}

// ---------------------------------------------------------------------------
extern "C" void kernel_launch(void* const* d_in, const int* in_sizes, int n_in,
                              void* d_out, int out_size, void* d_ws, size_t ws_size,
                              hipStream_t stream) {
  const float* img   = (const float*)d_in[0];
  const float* ln1_g = (const float*)d_in[1];
  const float* ln1_b = (const float*)d_in[2];
  const float* wqkv  = (const float*)d_in[3];
  const float* wo    = (const float*)d_in[4];
  const float* bo    = (const float*)d_in[5];
  const float* ln2_g = (const float*)d_in[6];
  const float* ln2_b = (const float*)d_in[7];
  const float* w1    = (const float*)d_in[8];
  const float* b1    = (const float*)d_in[9];
  const float* w2    = (const float*)d_in[10];
  const float* b2    = (const float*)d_in[11];
  float* out = (float*)d_out;

  char* ws = (char*)d_ws;
  float*          x   = (float*)ws;                         // 12,582,912
  unsigned short* xn  = (unsigned short*)(ws + 12582912);   //  6,291,456
  unsigned short* big = (unsigned short*)(ws + 18874368);   // 12,582,912
  unsigned short* ob  = (unsigned short*)(ws + 31457280);   //  3,145,728
  unsigned short* wtb = (unsigned short*)(ws + 34603008);   // weight area

  bool big_ws = (ws_size >= 110100480ull);
  size_t per_qkv = (size_t)1024 * 1536, per_o = (size_t)512 * 1024;
  size_t per_1   = (size_t)1024 * 2048, per_2 = (size_t)2048 * 1024;
  unsigned short *wt_qkv, *wt_o, *wt_1, *wt_2;
  if (big_ws) {
    wt_qkv = wtb;
    wt_o   = wt_qkv + 6 * per_qkv;
    wt_1   = wt_o   + 6 * per_o;
    wt_2   = wt_1   + 6 * per_1;
    wconv_k<<<dim3(1536 / 32, 1024 / 32, 6), 256, 0, stream>>>(wqkv, wt_qkv, 1024, 1536);
    wconv_k<<<dim3(1024 / 32,  512 / 32, 6), 256, 0, stream>>>(wo,   wt_o,    512, 1024);
    wconv_k<<<dim3(2048 / 32, 1024 / 32, 6), 256, 0, stream>>>(w1,   wt_1,   1024, 2048);
    wconv_k<<<dim3(1024 / 32, 2048 / 32, 6), 256, 0, stream>>>(w2,   wt_2,   2048, 1024);
  } else {
    wt_qkv = wtb;
    wt_o   = wt_qkv + per_qkv;
    wt_1   = wt_o + per_o;
    wt_2   = wt_1 + per_1;
  }

  preproc_k<<<16384, 64, 0, stream>>>(img, x);

  for (int l = 0; l < 6; ++l) {
    unsigned short *wq_l, *wo_l, *w1_l, *w2_l;
    if (big_ws) {
      wq_l = wt_qkv + l * per_qkv; wo_l = wt_o + l * per_o;
      w1_l = wt_1 + l * per_1;     w2_l = wt_2 + l * per_2;
    } else {
      wconv_k<<<dim3(1536 / 32, 1024 / 32), 256, 0, stream>>>(wqkv + l * per_qkv, wt_qkv, 1024, 1536);
      wconv_k<<<dim3(1024 / 32,  512 / 32), 256, 0, stream>>>(wo   + l * per_o,   wt_o,    512, 1024);
      wconv_k<<<dim3(2048 / 32, 1024 / 32), 256, 0, stream>>>(w1   + l * per_1,   wt_1,   1024, 2048);
      wconv_k<<<dim3(1024 / 32, 2048 / 32), 256, 0, stream>>>(w2   + l * per_2,   wt_2,   2048, 1024);
      wq_l = wt_qkv; wo_l = wt_o; w1_l = wt_1; w2_l = wt_2;
    }

    ln_k<<<MROWS, 256, 0, stream>>>(x, ln1_g + l * 1024, ln1_b + l * 1024, xn);
    mm_k<0><<<dim3(1536 / 64, 24), 512, 0, stream>>>(xn, wq_l, nullptr, nullptr, big, MROWS, 1536, 1024);
    attn_k<<<dim3(3, 8, 16), 256, 0, stream>>>(big, ob);
    mm_k<1><<<dim3(1024 / 64, 24), 512, 0, stream>>>(ob, wo_l, bo + l * 1024, x, x, MROWS, 1024, 512);
    ln_k<<<MROWS, 256, 0, stream>>>(x, ln2_g + l * 1024, ln2_b + l * 1024, xn);
    mm_k<2><<<dim3(2048 / 64, 24), 512, 0, stream>>>(xn, w1_l, b1 + l * 2048, nullptr, big, MROWS, 2048, 1024);
    mm_k<1><<<dim3(1024 / 64, 24), 512, 0, stream>>>(big, w2_l, b2 + l * 1024, x, x, MROWS, 1024, 2048);
  }

  postproc_k<<<16384, 64, 0, stream>>>(x, out);
}

// Round 7
// 810.267 us; speedup vs baseline: 5.5774x; 1.0666x over previous
//
#include <hip/hip_runtime.h>
#include <math.h>

// ---------------------------------------------------------------------------
// JPEG-domain ViT. Round 7:
//  - mm_k: counted-vmcnt pipeline (s_waitcnt vmcnt(3) + raw s_barrier, loads
//    stay in flight across the barrier) + T2 XOR swizzle (pre-swizzled global
//    source, linear global_load_lds dest, swizzled ds_read) -> 2-way max.
//  - preproc/postproc: LDS-staged, fully coalesced token writes/reads.
// ---------------------------------------------------------------------------

#define NIMG 16
#define SEQ 192
#define DIMV 1024
#define MROWS (NIMG * SEQ)   // 3072

typedef __attribute__((ext_vector_type(8))) short short8v;
typedef __attribute__((ext_vector_type(4))) float f32x4;
typedef unsigned int uint_t;

__device__ __forceinline__ unsigned short f2bf(float f) {
  union { float f; uint_t u; } x; x.f = f;
  uint_t r = x.u + 0x7fffu + ((x.u >> 16) & 1u);
  return (unsigned short)(r >> 16);
}

__device__ __forceinline__ void gload16(const void* g, void* l) {
  __builtin_amdgcn_global_load_lds(
      reinterpret_cast<const __attribute__((address_space(1))) void*>(
          reinterpret_cast<uintptr_t>(g)),
      reinterpret_cast<__attribute__((address_space(3))) void*>(
          reinterpret_cast<uintptr_t>(l)),
      16, 0, 0);
}

__constant__ float DCT8c[8][8] = {
  { 0.35355339f, 0.35355339f, 0.35355339f, 0.35355339f, 0.35355339f, 0.35355339f, 0.35355339f, 0.35355339f},
  { 0.49039264f, 0.41573481f, 0.27778512f, 0.09754516f,-0.09754516f,-0.27778512f,-0.41573481f,-0.49039264f},
  { 0.46193977f, 0.19134172f,-0.19134172f,-0.46193977f,-0.46193977f,-0.19134172f, 0.19134172f, 0.46193977f},
  { 0.41573481f,-0.09754516f,-0.49039264f,-0.27778512f, 0.27778512f, 0.49039264f, 0.09754516f,-0.41573481f},
  { 0.35355339f,-0.35355339f,-0.35355339f, 0.35355339f, 0.35355339f,-0.35355339f,-0.35355339f, 0.35355339f},
  { 0.27778512f,-0.49039264f, 0.09754516f, 0.41573481f,-0.41573481f,-0.09754516f, 0.49039264f,-0.27778512f},
  { 0.19134172f,-0.46193977f, 0.46193977f,-0.19134172f,-0.19134172f, 0.46193977f,-0.46193977f, 0.19134172f},
  { 0.09754516f,-0.27778512f, 0.41573481f,-0.49039264f, 0.49039264f,-0.41573481f, 0.27778512f,-0.09754516f}
};

// ---------------- preprocess (coalesced): block = (hb, n) ------------------
// Stages one 8-row stripe (all 3 channels) in LDS, does the 8x8 DCT in two
// passes, masks, writes tokens as 128B-contiguous rows.
__global__ __launch_bounds__(256) void preproc_k(const float* __restrict__ img,
                                                 float* __restrict__ x0) {
  int hb = blockIdx.x, n = blockIdx.y;
  __shared__ float yuv[3][8][256];   // [ch][i][x]
  __shared__ float tmpA[8][264];     // [p][x] (+pad)
  __shared__ float coefc[64][33];    // [s=p*8+q][wb] (+pad)
  int t = threadIdx.x;

  #pragma unroll
  for (int u = 0; u < 8; ++u) {
    int idx = u * 256 + t;
    int i = idx >> 8, xx = idx & 255;
    size_t pix = ((size_t)(n * 3) * 256 + hb * 8 + i) * 256 + xx;
    float r = img[pix], g = img[pix + 65536], b = img[pix + 131072];
    yuv[0][i][xx] =  0.299f   * r + 0.587f   * g + 0.114f   * b;
    yuv[1][i][xx] = -0.14713f * r - 0.28886f * g + 0.436f   * b;
    yuv[2][i][xx] =  0.615f   * r - 0.51499f * g - 0.10001f * b;
  }

  for (int c = 0; c < 3; ++c) {
    __syncthreads();
    // rows: tmpA[p][x] = sum_k D[p][k] * yuv[c][k][x]
    #pragma unroll
    for (int u = 0; u < 8; ++u) {
      int idx = u * 256 + t;
      int p = idx >> 8, xx = idx & 255;
      float a = 0.f;
      #pragma unroll
      for (int k = 0; k < 8; ++k) a += DCT8c[p][k] * yuv[c][k][xx];
      tmpA[p][xx] = a;
    }
    __syncthreads();
    // cols: coefc[p*8+q][wb] = sum_j tmpA[p][wb*8+j] * D[q][j], masked
    #pragma unroll
    for (int u = 0; u < 8; ++u) {
      int idx = u * 256 + t;
      int wb = idx >> 6, s = idx & 63;
      int p = s >> 3, qq = s & 7;
      float a = 0.f;
      #pragma unroll
      for (int j = 0; j < 8; ++j) a += tmpA[p][wb * 8 + j] * DCT8c[qq][j];
      bool keep = (c == 0) ? ((p + qq) <= 5 || ((p + qq) == 6 && qq < 4))
                           : ((p + qq) <= 2 || ((p + qq) == 3 && p < 3));
      coefc[s][wb] = keep ? a : 0.f;
    }
    __syncthreads();
    #pragma unroll
    for (int u = 0; u < 8; ++u) {
      int idx = u * 256 + t;
      int s = idx >> 5, wb = idx & 31;
      x0[((size_t)(n * SEQ) + c * 64 + s) * DIMV + hb * 32 + wb] = coefc[s][wb];
    }
  }
}

// ---------------- postprocess (coalesced): block = (hb, n) ------------------
__global__ __launch_bounds__(256) void postproc_k(const float* __restrict__ x,
                                                  float* __restrict__ out) {
  int hb = blockIdx.x, n = blockIdx.y;
  __shared__ float coefc[64][33];
  __shared__ float tmpA[8][264];
  __shared__ float rec[3][8][256];
  int t = threadIdx.x;

  for (int c = 0; c < 3; ++c) {
    __syncthreads();
    #pragma unroll
    for (int u = 0; u < 8; ++u) {
      int idx = u * 256 + t;
      int s = idx >> 5, wb = idx & 31;
      coefc[s][wb] = x[((size_t)(n * SEQ) + c * 64 + s) * DIMV + hb * 32 + wb];
    }
    __syncthreads();
    // tmpA[i][wb*8+q] = sum_p D[i][p] * coefc[p*8+q][wb]
    #pragma unroll
    for (int u = 0; u < 8; ++u) {
      int idx = u * 256 + t;
      int wb = idx >> 6, iq = idx & 63;
      int i = iq >> 3, qq = iq & 7;
      float a = 0.f;
      #pragma unroll
      for (int p = 0; p < 8; ++p) a += DCT8c[i][p] * coefc[p * 8 + qq][wb];
      tmpA[i][wb * 8 + qq] = a;
    }
    __syncthreads();
    // rec[c][i][wb*8+j] = sum_q tmpA[i][wb*8+q] * D[j][q]
    #pragma unroll
    for (int u = 0; u < 8; ++u) {
      int idx = u * 256 + t;
      int i = idx >> 8, xx = idx & 255;
      int wb = xx >> 3, j = xx & 7;
      float a = 0.f;
      #pragma unroll
      for (int qq = 0; qq < 8; ++qq) a += tmpA[i][wb * 8 + qq] * DCT8c[j][qq];
      rec[c][i][xx] = a;
    }
  }
  __syncthreads();
  #pragma unroll
  for (int u = 0; u < 8; ++u) {
    int idx = u * 256 + t;
    int i = idx >> 8, xx = idx & 255;
    float y = rec[0][i][xx], uu = rec[1][i][xx], v = rec[2][i][xx];
    size_t pix = ((size_t)(n * 3) * 256 + hb * 8 + i) * 256 + xx;
    out[pix]          = y + 1.13983f * v;
    out[pix + 65536]  = y - 0.39465f * uu - 0.5806f * v;
    out[pix + 131072] = y + 2.03211f * uu;
  }
}

// ---------------- weight transpose+convert: w[K][N] fp32 -> wt[N][K] bf16 ---
__global__ __launch_bounds__(256) void wconv_k(const float* __restrict__ w,
                                               unsigned short* __restrict__ wt,
                                               int K, int N) {
  size_t off = (size_t)blockIdx.z * K * N;
  w += off; wt += off;
  __shared__ float s[32][33];
  int t = threadIdx.x;
  int n0 = blockIdx.x << 5, k0 = blockIdx.y << 5;
  int r = t >> 3, c4 = (t & 7) << 2;
  float4 v = *(const float4*)(w + (size_t)(k0 + r) * N + n0 + c4);
  s[r][c4] = v.x; s[r][c4 + 1] = v.y; s[r][c4 + 2] = v.z; s[r][c4 + 3] = v.w;
  __syncthreads();
  ushort4 o;
  o.x = f2bf(s[c4 + 0][r]); o.y = f2bf(s[c4 + 1][r]);
  o.z = f2bf(s[c4 + 2][r]); o.w = f2bf(s[c4 + 3][r]);
  *(ushort4*)(wt + (size_t)(n0 + r) * K + k0 + c4) = o;
}

// ---------------- layernorm over last dim (1024): fp32 in -> bf16 out -------
__global__ __launch_bounds__(256) void ln_k(const float* __restrict__ x,
                                            const float* __restrict__ g,
                                            const float* __restrict__ b,
                                            unsigned short* __restrict__ out) {
  int row = blockIdx.x, t = threadIdx.x;
  float4 v = ((const float4*)(x + (size_t)row * DIMV))[t];
  float s  = v.x + v.y + v.z + v.w;
  float s2 = v.x * v.x + v.y * v.y + v.z * v.z + v.w * v.w;
  #pragma unroll
  for (int off = 32; off > 0; off >>= 1) {
    s  += __shfl_down(s,  off, 64);
    s2 += __shfl_down(s2, off, 64);
  }
  __shared__ float red[8];
  int w = t >> 6;
  if ((t & 63) == 0) { red[w] = s; red[4 + w] = s2; }
  __syncthreads();
  s  = red[0] + red[1] + red[2] + red[3];
  s2 = red[4] + red[5] + red[6] + red[7];
  float mu  = s * (1.f / 1024.f);
  float var = fmaxf(s2 * (1.f / 1024.f) - mu * mu, 0.f);
  float rs  = rsqrtf(var + 1e-5f);
  float4 gv = ((const float4*)g)[t];
  float4 bv = ((const float4*)b)[t];
  ushort4 ov;
  ov.x = f2bf((v.x - mu) * rs * gv.x + bv.x);
  ov.y = f2bf((v.y - mu) * rs * gv.y + bv.y);
  ov.z = f2bf((v.z - mu) * rs * gv.z + bv.z);
  ov.w = f2bf((v.w - mu) * rs * gv.w + bv.w);
  ((ushort4*)(out + (size_t)row * DIMV))[t] = ov;
}

// ---------------- bf16 MFMA GEMM: 128x64 tile, 8-wave split-K ---------------
// Counted-vmcnt double-buffer pipeline:
//   prologue: STAGE(0,db0), STAGE(1,db1)            (6 loads in flight/wave)
//   iter it : vmcnt(3) [own tile-it landed] -> s_barrier [all landed]
//             -> ds_read+MFMA(it) -> s_barrier [reads done]
//             -> STAGE(it+2) into db[it&1]          (back to 6 in flight)
// LDS bytes: A: db*16384 + half*8192 + row*64 (rows 0..127)
//            B: 32768 + db*8192 + half*4096 + row*64 (rows 0..63)
// T2 swizzle: 16B chunk c of row r lives at slot c ^ ((r>>1)&3); staging
// pre-swizzles the GLOBAL source (linear global_load_lds dest, rule #21).
// EPI: 0 = plain->bf16, 1 = +bias+fp32 residual->fp32, 2 = +bias+GELU->bf16
template <int EPI>
__global__ __launch_bounds__(512) void mm_k(const unsigned short* __restrict__ A,
                                            const unsigned short* __restrict__ Bt,
                                            const float* __restrict__ bias,
                                            const float* res,
                                            void* Cout,
                                            int M, int N, int K) {
  __shared__ __align__(16) unsigned short smem[24576];

  int t = threadIdx.x;
  int lane = t & 63, w = t >> 6;         // 8 waves
  int kh = w >> 2;                        // K-half this wave computes/stages B
  int q  = w & 3;                         // output quadrant
  int m0 = blockIdx.y << 7, n0 = blockIdx.x << 6;
  int wm = (q >> 1) << 6, wn = (q & 1) << 5;
  int Kh = K >> 1;

  // staging rows + swizzled global source chunk
  int ra = (w << 4) + (lane >> 2);                  // A row 0..127
  int rb = ((w & 3) << 4) + (lane >> 2);            // B row 0..63
  int ga = ((lane & 3) ^ ((ra >> 1) & 3)) << 3;     // src elem offset
  int gb = ((lane & 3) ^ ((rb >> 1) & 3)) << 3;
  const unsigned short* Ag = A + (size_t)(m0 + ra) * K + ga;
  const unsigned short* Bg = Bt + (size_t)(n0 + rb) * K + (size_t)kh * Kh + gb;
  char* smb = (char*)smem;

  f32x4 acc[4][2] = {};

  int c4 = lane >> 4;                               // frag k-chunk 0..3
  int fm = wm + (lane & 15);
  int fn = wn + (lane & 15);
  int sza = (c4 ^ ((fm >> 1) & 3)) << 4;            // swizzled read chunk byte
  int szb = (c4 ^ ((fn >> 1) & 3)) << 4;

  int nt = Kh >> 5;

  #define STAGE(it_, db_) {                                                   \
    int k0_ = (it_) << 5;                                                     \
    gload16(Ag + k0_,      smb + (db_) * 16384 + (w << 10));                  \
    gload16(Ag + k0_ + Kh, smb + (db_) * 16384 + 8192 + (w << 10));           \
    gload16(Bg + k0_,      smb + 32768 + (db_) * 8192 + (kh << 12) + ((w & 3) << 10)); }

  STAGE(0, 0);
  STAGE(1, 1);

  for (int it = 0; it < nt; ++it) {
    int db = it & 1;
    if (it + 1 < nt) asm volatile("s_waitcnt vmcnt(3)" ::: "memory");
    else             asm volatile("s_waitcnt vmcnt(0)" ::: "memory");
    __builtin_amdgcn_s_barrier();
    asm volatile("" ::: "memory");
    const char* Awb = smb + db * 16384 + (kh << 13);
    const char* Bwb = smb + 32768 + db * 8192 + (kh << 12);
    short8v a[4], b[2];
    #pragma unroll
    for (int mi = 0; mi < 4; ++mi)
      a[mi] = *(const short8v*)(Awb + (fm + mi * 16) * 64 + sza);
    #pragma unroll
    for (int ni = 0; ni < 2; ++ni)
      b[ni] = *(const short8v*)(Bwb + (fn + ni * 16) * 64 + szb);
    #pragma unroll
    for (int mi = 0; mi < 4; ++mi)
      #pragma unroll
      for (int ni = 0; ni < 2; ++ni)
        acc[mi][ni] = __builtin_amdgcn_mfma_f32_16x16x32_bf16(a[mi], b[ni], acc[mi][ni], 0, 0, 0);
    asm volatile("" ::: "memory");
    __builtin_amdgcn_s_barrier();
    if (it + 2 < nt) STAGE(it + 2, db);
  }
  #undef STAGE

  // ---- reduce waves 4-7 into waves 0-3 (staging LDS is dead now) ----------
  #pragma unroll
  for (int c = 0; c < 2; ++c) {
    if (w >= 4) {
      #pragma unroll
      for (int r = 0; r < 4; ++r)
        *(f32x4*)(smb + (((w - 4) * 4 + r) << 10) + (lane << 4)) =
            acc[2 * c + (r >> 1)][r & 1];
    }
    __syncthreads();
    if (w < 4) {
      #pragma unroll
      for (int r = 0; r < 4; ++r)
        acc[2 * c + (r >> 1)][r & 1] +=
            *(const f32x4*)(smb + ((w * 4 + r) << 10) + (lane << 4));
    }
    __syncthreads();
  }

  if (w >= 4) return;

  // epilogue: C/D frag layout col = lane&15, row = (lane>>4)*4 + r  [m89/m91]
  int cn = lane & 15;
  int rbq = (lane >> 4) << 2;
  #pragma unroll
  for (int mi = 0; mi < 4; ++mi) {
    #pragma unroll
    for (int ni = 0; ni < 2; ++ni) {
      int col = n0 + wn + ni * 16 + cn;
      #pragma unroll
      for (int r = 0; r < 4; ++r) {
        int row = m0 + wm + mi * 16 + rbq + r;
        float v = acc[mi][ni][r];
        if (EPI >= 1) v += bias[col];
        if (EPI == 1) {
          ((float*)Cout)[(size_t)row * N + col] = v + res[(size_t)row * N + col];
        } else if (EPI == 2) {
          v = 0.5f * v * (1.f + erff(v * 0.70710678f));
          ((unsigned short*)Cout)[(size_t)row * N + col] = f2bf(v);
        } else {
          ((unsigned short*)Cout)[(size_t)row * N + col] = f2bf(v);
        }
      }
    }
  }
}

// ---------------- MFMA attention (round 3, unchanged) -----------------------
__global__ __launch_bounds__(256) void attn_k(const unsigned short* __restrict__ qkv,
                                              unsigned short* __restrict__ o) {
  int qt = blockIdx.x, h = blockIdx.y, n = blockIdx.z;
  int t = threadIdx.x, lane = t & 63, w = t >> 6;
  __shared__ __align__(16) unsigned short Ks[192 * 64];
  __shared__ __align__(16) unsigned short Vt[64 * 192];
  __shared__ __align__(16) unsigned short Ps[4][16 * 192];
  const unsigned short* base = qkv + (size_t)n * SEQ * 1536;

  #pragma unroll
  for (int i = 0; i < 6; ++i) {
    int idx = i * 256 + t;
    int row = idx >> 3, c8 = (idx & 7) << 3;
    short8v kv = *(const short8v*)(base + (size_t)row * 1536 + 512 + h * 64 + c8);
    int kb = (row * 128 + c8 * 2) ^ ((row & 7) << 4);
    *(short8v*)((char*)Ks + kb) = kv;
  }
  #pragma unroll
  for (int i = 0; i < 6; ++i) {
    int idx = i * 256 + t;
    int j = (idx & 63) + ((idx >> 9) << 6);
    int d0 = ((idx >> 6) & 7) << 3;
    short8v vv = *(const short8v*)(base + (size_t)j * 1536 + 1024 + h * 64 + d0);
    #pragma unroll
    for (int e = 0; e < 8; ++e) {
      int d = d0 + e;
      int vb = (d * 384 + j * 2) ^ ((d & 7) << 4);
      *(unsigned short*)((char*)Vt + vb) = (unsigned short)vv[e];
    }
  }
  int q0 = qt * 64 + w * 16;
  const unsigned short* qp = base + (size_t)(q0 + (lane & 15)) * 1536 + h * 64 + ((lane >> 4) << 3);
  short8v aq0 = *(const short8v*)(qp);
  short8v aq1 = *(const short8v*)(qp + 32);
  __syncthreads();

  f32x4 sa[12];
  #pragma unroll
  for (int ni = 0; ni < 12; ++ni) sa[ni] = (f32x4){0.f, 0.f, 0.f, 0.f};
  #pragma unroll
  for (int ks = 0; ks < 2; ++ks) {
    int kk = (ks << 5) + ((lane >> 4) << 3);
    short8v aq = ks ? aq1 : aq0;
    #pragma unroll
    for (int ni = 0; ni < 12; ++ni) {
      int krow = ni * 16 + (lane & 15);
      int kb = (krow * 128 + kk * 2) ^ ((krow & 7) << 4);
      short8v bk = *(const short8v*)((char*)Ks + kb);
      sa[ni] = __builtin_amdgcn_mfma_f32_16x16x32_bf16(aq, bk, sa[ni], 0, 0, 0);
    }
  }

  unsigned short* Pw = Ps[w];
  float l4[4];
  #pragma unroll
  for (int r = 0; r < 4; ++r) {
    float mx = sa[0][r];
    #pragma unroll
    for (int ni = 1; ni < 12; ++ni) mx = fmaxf(mx, sa[ni][r]);
    mx = fmaxf(mx, __shfl_xor(mx, 1, 64));
    mx = fmaxf(mx, __shfl_xor(mx, 2, 64));
    mx = fmaxf(mx, __shfl_xor(mx, 4, 64));
    mx = fmaxf(mx, __shfl_xor(mx, 8, 64));
    int prow = ((lane >> 4) << 2) + r;
    float sum = 0.f;
    #pragma unroll
    for (int ni = 0; ni < 12; ++ni) {
      float p = __expf((sa[ni][r] - mx) * 0.125f);
      sum += p;
      int col = ni * 16 + (lane & 15);
      int pb = (prow * 384 + col * 2) ^ ((prow & 7) << 4);
      *(unsigned short*)((char*)Pw + pb) = f2bf(p);
    }
    sum += __shfl_xor(sum, 1, 64);
    sum += __shfl_xor(sum, 2, 64);
    sum += __shfl_xor(sum, 4, 64);
    sum += __shfl_xor(sum, 8, 64);
    l4[r] = sum;
  }

  f32x4 oa[4];
  #pragma unroll
  for (int ni = 0; ni < 4; ++ni) oa[ni] = (f32x4){0.f, 0.f, 0.f, 0.f};
  #pragma unroll
  for (int ks = 0; ks < 6; ++ks) {
    int kk = (ks << 5) + ((lane >> 4) << 3);
    int m = lane & 15;
    int pb = (m * 384 + kk * 2) ^ ((m & 7) << 4);
    short8v pa = *(const short8v*)((char*)Pw + pb);
    #pragma unroll
    for (int ni = 0; ni < 4; ++ni) {
      int vrow = ni * 16 + (lane & 15);
      int vb = (vrow * 384 + kk * 2) ^ ((vrow & 7) << 4);
      short8v vbf = *(const short8v*)((char*)Vt + vb);
      oa[ni] = __builtin_amdgcn_mfma_f32_16x16x32_bf16(pa, vbf, oa[ni], 0, 0, 0);
    }
  }

  int rbq = (lane >> 4) << 2;
  #pragma unroll
  for (int r = 0; r < 4; ++r) {
    float inv = 1.f / l4[r];
    unsigned short* dst = o + (size_t)(n * SEQ + q0 + rbq + r) * 512 + h * 64 + (lane & 15);
    #pragma unroll
    for (int ni = 0; ni < 4; ++ni)
      dst[ni * 16] = f2bf(oa[ni][r] * inv);
  }
}

// ---------------------------------------------------------------------------
extern "C" void kernel_launch(void* const* d_in, const int* in_sizes, int n_in,
                              void* d_out, int out_size, void* d_ws, size_t ws_size,
                              hipStream_t stream) {
  const float* img   = (const float*)d_in[0];
  const float* ln1_g = (const float*)d_in[1];
  const float* ln1_b = (const float*)d_in[2];
  const float* wqkv  = (const float*)d_in[3];
  const float* wo    = (const float*)d_in[4];
  const float* bo    = (const float*)d_in[5];
  const float* ln2_g = (const float*)d_in[6];
  const float* ln2_b = (const float*)d_in[7];
  const float* w1    = (const float*)d_in[8];
  const float* b1    = (const float*)d_in[9];
  const float* w2    = (const float*)d_in[10];
  const float* b2    = (const float*)d_in[11];
  float* out = (float*)d_out;

  char* ws = (char*)d_ws;
  float*          x   = (float*)ws;                         // 12,582,912
  unsigned short* xn  = (unsigned short*)(ws + 12582912);   //  6,291,456
  unsigned short* big = (unsigned short*)(ws + 18874368);   // 12,582,912
  unsigned short* ob  = (unsigned short*)(ws + 31457280);   //  3,145,728
  unsigned short* wtb = (unsigned short*)(ws + 34603008);   // weight area

  bool big_ws = (ws_size >= 110100480ull);
  size_t per_qkv = (size_t)1024 * 1536, per_o = (size_t)512 * 1024;
  size_t per_1   = (size_t)1024 * 2048, per_2 = (size_t)2048 * 1024;
  unsigned short *wt_qkv, *wt_o, *wt_1, *wt_2;
  if (big_ws) {
    wt_qkv = wtb;
    wt_o   = wt_qkv + 6 * per_qkv;
    wt_1   = wt_o   + 6 * per_o;
    wt_2   = wt_1   + 6 * per_1;
    wconv_k<<<dim3(1536 / 32, 1024 / 32, 6), 256, 0, stream>>>(wqkv, wt_qkv, 1024, 1536);
    wconv_k<<<dim3(1024 / 32,  512 / 32, 6), 256, 0, stream>>>(wo,   wt_o,    512, 1024);
    wconv_k<<<dim3(2048 / 32, 1024 / 32, 6), 256, 0, stream>>>(w1,   wt_1,   1024, 2048);
    wconv_k<<<dim3(1024 / 32, 2048 / 32, 6), 256, 0, stream>>>(w2,   wt_2,   2048, 1024);
  } else {
    wt_qkv = wtb;
    wt_o   = wt_qkv + per_qkv;
    wt_1   = wt_o + per_o;
    wt_2   = wt_1 + per_1;
  }

  preproc_k<<<dim3(32, 16), 256, 0, stream>>>(img, x);

  for (int l = 0; l < 6; ++l) {
    unsigned short *wq_l, *wo_l, *w1_l, *w2_l;
    if (big_ws) {
      wq_l = wt_qkv + l * per_qkv; wo_l = wt_o + l * per_o;
      w1_l = wt_1 + l * per_1;     w2_l = wt_2 + l * per_2;
    } else {
      wconv_k<<<dim3(1536 / 32, 1024 / 32), 256, 0, stream>>>(wqkv + l * per_qkv, wt_qkv, 1024, 1536);
      wconv_k<<<dim3(1024 / 32,  512 / 32), 256, 0, stream>>>(wo   + l * per_o,   wt_o,    512, 1024);
      wconv_k<<<dim3(2048 / 32, 1024 / 32), 256, 0, stream>>>(w1   + l * per_1,   wt_1,   1024, 2048);
      wconv_k<<<dim3(1024 / 32, 2048 / 32), 256, 0, stream>>>(w2   + l * per_2,   wt_2,   2048, 1024);
      wq_l = wt_qkv; wo_l = wt_o; w1_l = wt_1; w2_l = wt_2;
    }

    ln_k<<<MROWS, 256, 0, stream>>>(x, ln1_g + l * 1024, ln1_b + l * 1024, xn);
    mm_k<0><<<dim3(1536 / 64, 24), 512, 0, stream>>>(xn, wq_l, nullptr, nullptr, big, MROWS, 1536, 1024);
    attn_k<<<dim3(3, 8, 16), 256, 0, stream>>>(big, ob);
    mm_k<1><<<dim3(1024 / 64, 24), 512, 0, stream>>>(ob, wo_l, bo + l * 1024, x, x, MROWS, 1024, 512);
    ln_k<<<MROWS, 256, 0, stream>>>(x, ln2_g + l * 1024, ln2_b + l * 1024, xn);
    mm_k<2><<<dim3(2048 / 64, 24), 512, 0, stream>>>(xn, w1_l, b1 + l * 2048, nullptr, big, MROWS, 2048, 1024);
    mm_k<1><<<dim3(1024 / 64, 24), 512, 0, stream>>>(big, w2_l, b2 + l * 1024, x, x, MROWS, 1024, 2048);
  }

  postproc_k<<<dim3(32, 16), 256, 0, stream>>>(x, out);
}

// Round 8
// 658.322 us; speedup vs baseline: 6.8647x; 1.2308x over previous
//
#include <hip/hip_runtime.h>
#include <math.h>

// ---------------------------------------------------------------------------
// JPEG-domain ViT. Round 8: mm_k rebuilt around request-rate analysis:
//   BK=64, 128x64 tile, 4 waves, no split-K. Each global_load_lds now moves
//   8 rows x 128 B = 8 FULL cache lines (was 16 half-lines) -> halves TA
//   requests and HBM fetch. Counted vmcnt(6) 2-deep pipeline, 8-chunk XOR
//   swizzle (global-source pre-swizzle + swizzled ds_read), XCD swizzle.
// ---------------------------------------------------------------------------

#define NIMG 16
#define SEQ 192
#define DIMV 1024
#define MROWS (NIMG * SEQ)   // 3072

typedef __attribute__((ext_vector_type(8))) short short8v;
typedef __attribute__((ext_vector_type(4))) float f32x4;
typedef unsigned int uint_t;

__device__ __forceinline__ unsigned short f2bf(float f) {
  union { float f; uint_t u; } x; x.f = f;
  uint_t r = x.u + 0x7fffu + ((x.u >> 16) & 1u);
  return (unsigned short)(r >> 16);
}

__device__ __forceinline__ void gload16(const void* g, void* l) {
  __builtin_amdgcn_global_load_lds(
      reinterpret_cast<const __attribute__((address_space(1))) void*>(
          reinterpret_cast<uintptr_t>(g)),
      reinterpret_cast<__attribute__((address_space(3))) void*>(
          reinterpret_cast<uintptr_t>(l)),
      16, 0, 0);
}

__constant__ float DCT8c[8][8] = {
  { 0.35355339f, 0.35355339f, 0.35355339f, 0.35355339f, 0.35355339f, 0.35355339f, 0.35355339f, 0.35355339f},
  { 0.49039264f, 0.41573481f, 0.27778512f, 0.09754516f,-0.09754516f,-0.27778512f,-0.41573481f,-0.49039264f},
  { 0.46193977f, 0.19134172f,-0.19134172f,-0.46193977f,-0.46193977f,-0.19134172f, 0.19134172f, 0.46193977f},
  { 0.41573481f,-0.09754516f,-0.49039264f,-0.27778512f, 0.27778512f, 0.49039264f, 0.09754516f,-0.41573481f},
  { 0.35355339f,-0.35355339f,-0.35355339f, 0.35355339f, 0.35355339f,-0.35355339f,-0.35355339f, 0.35355339f},
  { 0.27778512f,-0.49039264f, 0.09754516f, 0.41573481f,-0.41573481f,-0.09754516f, 0.49039264f,-0.27778512f},
  { 0.19134172f,-0.46193977f, 0.46193977f,-0.19134172f,-0.19134172f, 0.46193977f,-0.46193977f, 0.19134172f},
  { 0.09754516f,-0.27778512f, 0.41573481f,-0.49039264f, 0.49039264f,-0.41573481f, 0.27778512f,-0.09754516f}
};

// ---------------- preprocess (coalesced): block = (hb, n) ------------------
__global__ __launch_bounds__(256) void preproc_k(const float* __restrict__ img,
                                                 float* __restrict__ x0) {
  int hb = blockIdx.x, n = blockIdx.y;
  __shared__ float yuv[3][8][256];
  __shared__ float tmpA[8][264];
  __shared__ float coefc[64][33];
  int t = threadIdx.x;

  #pragma unroll
  for (int u = 0; u < 8; ++u) {
    int idx = u * 256 + t;
    int i = idx >> 8, xx = idx & 255;
    size_t pix = ((size_t)(n * 3) * 256 + hb * 8 + i) * 256 + xx;
    float r = img[pix], g = img[pix + 65536], b = img[pix + 131072];
    yuv[0][i][xx] =  0.299f   * r + 0.587f   * g + 0.114f   * b;
    yuv[1][i][xx] = -0.14713f * r - 0.28886f * g + 0.436f   * b;
    yuv[2][i][xx] =  0.615f   * r - 0.51499f * g - 0.10001f * b;
  }

  for (int c = 0; c < 3; ++c) {
    __syncthreads();
    #pragma unroll
    for (int u = 0; u < 8; ++u) {
      int idx = u * 256 + t;
      int p = idx >> 8, xx = idx & 255;
      float a = 0.f;
      #pragma unroll
      for (int k = 0; k < 8; ++k) a += DCT8c[p][k] * yuv[c][k][xx];
      tmpA[p][xx] = a;
    }
    __syncthreads();
    #pragma unroll
    for (int u = 0; u < 8; ++u) {
      int idx = u * 256 + t;
      int wb = idx >> 6, s = idx & 63;
      int p = s >> 3, qq = s & 7;
      float a = 0.f;
      #pragma unroll
      for (int j = 0; j < 8; ++j) a += tmpA[p][wb * 8 + j] * DCT8c[qq][j];
      bool keep = (c == 0) ? ((p + qq) <= 5 || ((p + qq) == 6 && qq < 4))
                           : ((p + qq) <= 2 || ((p + qq) == 3 && p < 3));
      coefc[s][wb] = keep ? a : 0.f;
    }
    __syncthreads();
    #pragma unroll
    for (int u = 0; u < 8; ++u) {
      int idx = u * 256 + t;
      int s = idx >> 5, wb = idx & 31;
      x0[((size_t)(n * SEQ) + c * 64 + s) * DIMV + hb * 32 + wb] = coefc[s][wb];
    }
  }
}

// ---------------- postprocess (coalesced): block = (hb, n) ------------------
__global__ __launch_bounds__(256) void postproc_k(const float* __restrict__ x,
                                                  float* __restrict__ out) {
  int hb = blockIdx.x, n = blockIdx.y;
  __shared__ float coefc[64][33];
  __shared__ float tmpA[8][264];
  __shared__ float rec[3][8][256];
  int t = threadIdx.x;

  for (int c = 0; c < 3; ++c) {
    __syncthreads();
    #pragma unroll
    for (int u = 0; u < 8; ++u) {
      int idx = u * 256 + t;
      int s = idx >> 5, wb = idx & 31;
      coefc[s][wb] = x[((size_t)(n * SEQ) + c * 64 + s) * DIMV + hb * 32 + wb];
    }
    __syncthreads();
    #pragma unroll
    for (int u = 0; u < 8; ++u) {
      int idx = u * 256 + t;
      int wb = idx >> 6, iq = idx & 63;
      int i = iq >> 3, qq = iq & 7;
      float a = 0.f;
      #pragma unroll
      for (int p = 0; p < 8; ++p) a += DCT8c[i][p] * coefc[p * 8 + qq][wb];
      tmpA[i][wb * 8 + qq] = a;
    }
    __syncthreads();
    #pragma unroll
    for (int u = 0; u < 8; ++u) {
      int idx = u * 256 + t;
      int i = idx >> 8, xx = idx & 255;
      int wb = xx >> 3, j = xx & 7;
      float a = 0.f;
      #pragma unroll
      for (int qq = 0; qq < 8; ++qq) a += tmpA[i][wb * 8 + qq] * DCT8c[j][qq];
      rec[c][i][xx] = a;
    }
  }
  __syncthreads();
  #pragma unroll
  for (int u = 0; u < 8; ++u) {
    int idx = u * 256 + t;
    int i = idx >> 8, xx = idx & 255;
    float y = rec[0][i][xx], uu = rec[1][i][xx], v = rec[2][i][xx];
    size_t pix = ((size_t)(n * 3) * 256 + hb * 8 + i) * 256 + xx;
    out[pix]          = y + 1.13983f * v;
    out[pix + 65536]  = y - 0.39465f * uu - 0.5806f * v;
    out[pix + 131072] = y + 2.03211f * uu;
  }
}

// ---------------- weight transpose+convert: w[K][N] fp32 -> wt[N][K] bf16 ---
__global__ __launch_bounds__(256) void wconv_k(const float* __restrict__ w,
                                               unsigned short* __restrict__ wt,
                                               int K, int N) {
  size_t off = (size_t)blockIdx.z * K * N;
  w += off; wt += off;
  __shared__ float s[32][33];
  int t = threadIdx.x;
  int n0 = blockIdx.x << 5, k0 = blockIdx.y << 5;
  int r = t >> 3, c4 = (t & 7) << 2;
  float4 v = *(const float4*)(w + (size_t)(k0 + r) * N + n0 + c4);
  s[r][c4] = v.x; s[r][c4 + 1] = v.y; s[r][c4 + 2] = v.z; s[r][c4 + 3] = v.w;
  __syncthreads();
  ushort4 o;
  o.x = f2bf(s[c4 + 0][r]); o.y = f2bf(s[c4 + 1][r]);
  o.z = f2bf(s[c4 + 2][r]); o.w = f2bf(s[c4 + 3][r]);
  *(ushort4*)(wt + (size_t)(n0 + r) * K + k0 + c4) = o;
}

// ---------------- layernorm over last dim (1024): fp32 in -> bf16 out -------
__global__ __launch_bounds__(256) void ln_k(const float* __restrict__ x,
                                            const float* __restrict__ g,
                                            const float* __restrict__ b,
                                            unsigned short* __restrict__ out) {
  int row = blockIdx.x, t = threadIdx.x;
  float4 v = ((const float4*)(x + (size_t)row * DIMV))[t];
  float s  = v.x + v.y + v.z + v.w;
  float s2 = v.x * v.x + v.y * v.y + v.z * v.z + v.w * v.w;
  #pragma unroll
  for (int off = 32; off > 0; off >>= 1) {
    s  += __shfl_down(s,  off, 64);
    s2 += __shfl_down(s2, off, 64);
  }
  __shared__ float red[8];
  int w = t >> 6;
  if ((t & 63) == 0) { red[w] = s; red[4 + w] = s2; }
  __syncthreads();
  s  = red[0] + red[1] + red[2] + red[3];
  s2 = red[4] + red[5] + red[6] + red[7];
  float mu  = s * (1.f / 1024.f);
  float var = fmaxf(s2 * (1.f / 1024.f) - mu * mu, 0.f);
  float rs  = rsqrtf(var + 1e-5f);
  float4 gv = ((const float4*)g)[t];
  float4 bv = ((const float4*)b)[t];
  ushort4 ov;
  ov.x = f2bf((v.x - mu) * rs * gv.x + bv.x);
  ov.y = f2bf((v.y - mu) * rs * gv.y + bv.y);
  ov.z = f2bf((v.z - mu) * rs * gv.z + bv.z);
  ov.w = f2bf((v.w - mu) * rs * gv.w + bv.w);
  ((ushort4*)(out + (size_t)row * DIMV))[t] = ov;
}

// ---------------- bf16 MFMA GEMM: 128x64 tile, 4 waves, BK=64 ---------------
// C[M,N] = A[M,K] @ Bt[N,K]^T. Wave w: quadrant (wm=(w>>1)*64, wn=(w&1)*32),
// full K (no split-K). Per step (BK=64): 12 ds_read_b128 + 16 MFMA.
// Staging: gload16 covers 8 rows x 128 B -> 8 FULL cache lines/instr.
// Swizzle: physical 16B chunk p of row r holds logical chunk p^(r&7);
// lane loads global chunk (lane&7)^(lane>>3) (involution, rule #21).
// Pipeline: STAGE(0),STAGE(1); per it: vmcnt(6) -> s_barrier -> compute(it)
//           -> s_barrier -> STAGE(it+2). 6 loads/wave stay in flight.
// LDS: A[db] = db*16KB (128 rows x 128 B); B[db] = 32KB + db*8KB (64 rows).
// EPI: 0 = plain->bf16, 1 = +bias+fp32 residual->fp32, 2 = +bias+GELU->bf16
template <int EPI>
__global__ __launch_bounds__(256) void mm_k(const unsigned short* __restrict__ A,
                                            const unsigned short* __restrict__ Bt,
                                            const float* __restrict__ bias,
                                            const float* res,
                                            void* Cout,
                                            int M, int N, int K) {
  __shared__ __align__(16) unsigned short smem[24576];   // 48 KB

  int t = threadIdx.x;
  int lane = t & 63, w = t >> 6;          // 4 waves
  // bijective XCD swizzle (all grids here are divisible by 8)
  int gx = gridDim.x;
  int nwg = gx * gridDim.y;
  int bid = blockIdx.y * gx + blockIdx.x;
  bid = (bid & 7) * (nwg >> 3) + (bid >> 3);
  int m0 = (bid / gx) << 7, n0 = (bid % gx) << 6;
  int wm = (w >> 1) << 6, wn = (w & 1) << 5;

  // staging: lane -> row offset r_in = lane>>3, physical chunk p = lane&7,
  // loads logical chunk p^r_in (8 elems) of its row.
  int r_in = lane >> 3, p = lane & 7;
  int sw = (p ^ r_in) << 3;
  const unsigned short* Ag = A + (size_t)(m0 + w * 32 + r_in) * K + sw;
  const unsigned short* Bg = Bt + (size_t)(n0 + w * 16 + r_in) * K + sw;
  char* smb = (char*)smem;
  size_t K8 = (size_t)K * 8;

  f32x4 acc[4][2] = {};

  int m15 = lane & 15, c4 = lane >> 4, s7 = lane & 7;
  int nt = K >> 6;

  #define STAGE(it_, db_) {                                                    \
    size_t k0_ = (size_t)(it_) << 6;                                           \
    gload16(Ag + k0_,          smb + (db_) * 16384 + ((w * 32 +  0) << 7));    \
    gload16(Ag + k0_ + K8,     smb + (db_) * 16384 + ((w * 32 +  8) << 7));    \
    gload16(Ag + k0_ + 2 * K8, smb + (db_) * 16384 + ((w * 32 + 16) << 7));    \
    gload16(Ag + k0_ + 3 * K8, smb + (db_) * 16384 + ((w * 32 + 24) << 7));    \
    gload16(Bg + k0_,          smb + 32768 + (db_) * 8192 + ((w * 16 + 0) << 7)); \
    gload16(Bg + k0_ + K8,     smb + 32768 + (db_) * 8192 + ((w * 16 + 8) << 7)); }

  STAGE(0, 0);
  STAGE(1, 1);

  for (int it = 0; it < nt; ++it) {
    int db = it & 1;
    if (it + 1 < nt) asm volatile("s_waitcnt vmcnt(6)" ::: "memory");
    else             asm volatile("s_waitcnt vmcnt(0)" ::: "memory");
    __builtin_amdgcn_s_barrier();
    const char* Ab = smb + db * 16384;
    const char* Bb = smb + 32768 + db * 8192;
    short8v a[2][4], b[2][2];
    #pragma unroll
    for (int kc = 0; kc < 2; ++kc) {
      int ch = ((kc << 2) + c4);
      #pragma unroll
      for (int mi = 0; mi < 4; ++mi)
        a[kc][mi] = *(const short8v*)(Ab + ((wm + mi * 16 + m15) << 7) + ((ch ^ s7) << 4));
      #pragma unroll
      for (int ni = 0; ni < 2; ++ni)
        b[kc][ni] = *(const short8v*)(Bb + ((wn + ni * 16 + m15) << 7) + ((ch ^ s7) << 4));
    }
    #pragma unroll
    for (int kc = 0; kc < 2; ++kc)
      #pragma unroll
      for (int mi = 0; mi < 4; ++mi)
        #pragma unroll
        for (int ni = 0; ni < 2; ++ni)
          acc[mi][ni] = __builtin_amdgcn_mfma_f32_16x16x32_bf16(a[kc][mi], b[kc][ni], acc[mi][ni], 0, 0, 0);
    __builtin_amdgcn_s_barrier();
    if (it + 2 < nt) STAGE(it + 2, db);
  }
  #undef STAGE

  // epilogue: C/D frag layout col = lane&15, row = (lane>>4)*4 + r  [m89/m91]
  int cn = lane & 15;
  int rbq = (lane >> 4) << 2;
  #pragma unroll
  for (int mi = 0; mi < 4; ++mi) {
    #pragma unroll
    for (int ni = 0; ni < 2; ++ni) {
      int col = n0 + wn + ni * 16 + cn;
      #pragma unroll
      for (int r = 0; r < 4; ++r) {
        int row = m0 + wm + mi * 16 + rbq + r;
        float v = acc[mi][ni][r];
        if (EPI >= 1) v += bias[col];
        if (EPI == 1) {
          ((float*)Cout)[(size_t)row * N + col] = v + res[(size_t)row * N + col];
        } else if (EPI == 2) {
          v = 0.5f * v * (1.f + erff(v * 0.70710678f));
          ((unsigned short*)Cout)[(size_t)row * N + col] = f2bf(v);
        } else {
          ((unsigned short*)Cout)[(size_t)row * N + col] = f2bf(v);
        }
      }
    }
  }
}

// ---------------- MFMA attention (round 3, unchanged) -----------------------
__global__ __launch_bounds__(256) void attn_k(const unsigned short* __restrict__ qkv,
                                              unsigned short* __restrict__ o) {
  int qt = blockIdx.x, h = blockIdx.y, n = blockIdx.z;
  int t = threadIdx.x, lane = t & 63, w = t >> 6;
  __shared__ __align__(16) unsigned short Ks[192 * 64];
  __shared__ __align__(16) unsigned short Vt[64 * 192];
  __shared__ __align__(16) unsigned short Ps[4][16 * 192];
  const unsigned short* base = qkv + (size_t)n * SEQ * 1536;

  #pragma unroll
  for (int i = 0; i < 6; ++i) {
    int idx = i * 256 + t;
    int row = idx >> 3, c8 = (idx & 7) << 3;
    short8v kv = *(const short8v*)(base + (size_t)row * 1536 + 512 + h * 64 + c8);
    int kb = (row * 128 + c8 * 2) ^ ((row & 7) << 4);
    *(short8v*)((char*)Ks + kb) = kv;
  }
  #pragma unroll
  for (int i = 0; i < 6; ++i) {
    int idx = i * 256 + t;
    int j = (idx & 63) + ((idx >> 9) << 6);
    int d0 = ((idx >> 6) & 7) << 3;
    short8v vv = *(const short8v*)(base + (size_t)j * 1536 + 1024 + h * 64 + d0);
    #pragma unroll
    for (int e = 0; e < 8; ++e) {
      int d = d0 + e;
      int vb = (d * 384 + j * 2) ^ ((d & 7) << 4);
      *(unsigned short*)((char*)Vt + vb) = (unsigned short)vv[e];
    }
  }
  int q0 = qt * 64 + w * 16;
  const unsigned short* qp = base + (size_t)(q0 + (lane & 15)) * 1536 + h * 64 + ((lane >> 4) << 3);
  short8v aq0 = *(const short8v*)(qp);
  short8v aq1 = *(const short8v*)(qp + 32);
  __syncthreads();

  f32x4 sa[12];
  #pragma unroll
  for (int ni = 0; ni < 12; ++ni) sa[ni] = (f32x4){0.f, 0.f, 0.f, 0.f};
  #pragma unroll
  for (int ks = 0; ks < 2; ++ks) {
    int kk = (ks << 5) + ((lane >> 4) << 3);
    short8v aq = ks ? aq1 : aq0;
    #pragma unroll
    for (int ni = 0; ni < 12; ++ni) {
      int krow = ni * 16 + (lane & 15);
      int kb = (krow * 128 + kk * 2) ^ ((krow & 7) << 4);
      short8v bk = *(const short8v*)((char*)Ks + kb);
      sa[ni] = __builtin_amdgcn_mfma_f32_16x16x32_bf16(aq, bk, sa[ni], 0, 0, 0);
    }
  }

  unsigned short* Pw = Ps[w];
  float l4[4];
  #pragma unroll
  for (int r = 0; r < 4; ++r) {
    float mx = sa[0][r];
    #pragma unroll
    for (int ni = 1; ni < 12; ++ni) mx = fmaxf(mx, sa[ni][r]);
    mx = fmaxf(mx, __shfl_xor(mx, 1, 64));
    mx = fmaxf(mx, __shfl_xor(mx, 2, 64));
    mx = fmaxf(mx, __shfl_xor(mx, 4, 64));
    mx = fmaxf(mx, __shfl_xor(mx, 8, 64));
    int prow = ((lane >> 4) << 2) + r;
    float sum = 0.f;
    #pragma unroll
    for (int ni = 0; ni < 12; ++ni) {
      float p = __expf((sa[ni][r] - mx) * 0.125f);
      sum += p;
      int col = ni * 16 + (lane & 15);
      int pb = (prow * 384 + col * 2) ^ ((prow & 7) << 4);
      *(unsigned short*)((char*)Pw + pb) = f2bf(p);
    }
    sum += __shfl_xor(sum, 1, 64);
    sum += __shfl_xor(sum, 2, 64);
    sum += __shfl_xor(sum, 4, 64);
    sum += __shfl_xor(sum, 8, 64);
    l4[r] = sum;
  }

  f32x4 oa[4];
  #pragma unroll
  for (int ni = 0; ni < 4; ++ni) oa[ni] = (f32x4){0.f, 0.f, 0.f, 0.f};
  #pragma unroll
  for (int ks = 0; ks < 6; ++ks) {
    int kk = (ks << 5) + ((lane >> 4) << 3);
    int m = lane & 15;
    int pb = (m * 384 + kk * 2) ^ ((m & 7) << 4);
    short8v pa = *(const short8v*)((char*)Pw + pb);
    #pragma unroll
    for (int ni = 0; ni < 4; ++ni) {
      int vrow = ni * 16 + (lane & 15);
      int vb = (vrow * 384 + kk * 2) ^ ((vrow & 7) << 4);
      short8v vbf = *(const short8v*)((char*)Vt + vb);
      oa[ni] = __builtin_amdgcn_mfma_f32_16x16x32_bf16(pa, vbf, oa[ni], 0, 0, 0);
    }
  }

  int rbq = (lane >> 4) << 2;
  #pragma unroll
  for (int r = 0; r < 4; ++r) {
    float inv = 1.f / l4[r];
    unsigned short* dst = o + (size_t)(n * SEQ + q0 + rbq + r) * 512 + h * 64 + (lane & 15);
    #pragma unroll
    for (int ni = 0; ni < 4; ++ni)
      dst[ni * 16] = f2bf(oa[ni][r] * inv);
  }
}

// ---------------------------------------------------------------------------
extern "C" void kernel_launch(void* const* d_in, const int* in_sizes, int n_in,
                              void* d_out, int out_size, void* d_ws, size_t ws_size,
                              hipStream_t stream) {
  const float* img   = (const float*)d_in[0];
  const float* ln1_g = (const float*)d_in[1];
  const float* ln1_b = (const float*)d_in[2];
  const float* wqkv  = (const float*)d_in[3];
  const float* wo    = (const float*)d_in[4];
  const float* bo    = (const float*)d_in[5];
  const float* ln2_g = (const float*)d_in[6];
  const float* ln2_b = (const float*)d_in[7];
  const float* w1    = (const float*)d_in[8];
  const float* b1    = (const float*)d_in[9];
  const float* w2    = (const float*)d_in[10];
  const float* b2    = (const float*)d_in[11];
  float* out = (float*)d_out;

  char* ws = (char*)d_ws;
  float*          x   = (float*)ws;                         // 12,582,912
  unsigned short* xn  = (unsigned short*)(ws + 12582912);   //  6,291,456
  unsigned short* big = (unsigned short*)(ws + 18874368);   // 12,582,912
  unsigned short* ob  = (unsigned short*)(ws + 31457280);   //  3,145,728
  unsigned short* wtb = (unsigned short*)(ws + 34603008);   // weight area

  bool big_ws = (ws_size >= 110100480ull);
  size_t per_qkv = (size_t)1024 * 1536, per_o = (size_t)512 * 1024;
  size_t per_1   = (size_t)1024 * 2048, per_2 = (size_t)2048 * 1024;
  unsigned short *wt_qkv, *wt_o, *wt_1, *wt_2;
  if (big_ws) {
    wt_qkv = wtb;
    wt_o   = wt_qkv + 6 * per_qkv;
    wt_1   = wt_o   + 6 * per_o;
    wt_2   = wt_1   + 6 * per_1;
    wconv_k<<<dim3(1536 / 32, 1024 / 32, 6), 256, 0, stream>>>(wqkv, wt_qkv, 1024, 1536);
    wconv_k<<<dim3(1024 / 32,  512 / 32, 6), 256, 0, stream>>>(wo,   wt_o,    512, 1024);
    wconv_k<<<dim3(2048 / 32, 1024 / 32, 6), 256, 0, stream>>>(w1,   wt_1,   1024, 2048);
    wconv_k<<<dim3(1024 / 32, 2048 / 32, 6), 256, 0, stream>>>(w2,   wt_2,   2048, 1024);
  } else {
    wt_qkv = wtb;
    wt_o   = wt_qkv + per_qkv;
    wt_1   = wt_o + per_o;
    wt_2   = wt_1 + per_1;
  }

  preproc_k<<<dim3(32, 16), 256, 0, stream>>>(img, x);

  for (int l = 0; l < 6; ++l) {
    unsigned short *wq_l, *wo_l, *w1_l, *w2_l;
    if (big_ws) {
      wq_l = wt_qkv + l * per_qkv; wo_l = wt_o + l * per_o;
      w1_l = wt_1 + l * per_1;     w2_l = wt_2 + l * per_2;
    } else {
      wconv_k<<<dim3(1536 / 32, 1024 / 32), 256, 0, stream>>>(wqkv + l * per_qkv, wt_qkv, 1024, 1536);
      wconv_k<<<dim3(1024 / 32,  512 / 32), 256, 0, stream>>>(wo   + l * per_o,   wt_o,    512, 1024);
      wconv_k<<<dim3(2048 / 32, 1024 / 32), 256, 0, stream>>>(w1   + l * per_1,   wt_1,   1024, 2048);
      wconv_k<<<dim3(1024 / 32, 2048 / 32), 256, 0, stream>>>(w2   + l * per_2,   wt_2,   2048, 1024);
      wq_l = wt_qkv; wo_l = wt_o; w1_l = wt_1; w2_l = wt_2;
    }

    ln_k<<<MROWS, 256, 0, stream>>>(x, ln1_g + l * 1024, ln1_b + l * 1024, xn);
    mm_k<0><<<dim3(1536 / 64, 24), 256, 0, stream>>>(xn, wq_l, nullptr, nullptr, big, MROWS, 1536, 1024);
    attn_k<<<dim3(3, 8, 16), 256, 0, stream>>>(big, ob);
    mm_k<1><<<dim3(1024 / 64, 24), 256, 0, stream>>>(ob, wo_l, bo + l * 1024, x, x, MROWS, 1024, 512);
    ln_k<<<MROWS, 256, 0, stream>>>(x, ln2_g + l * 1024, ln2_b + l * 1024, xn);
    mm_k<2><<<dim3(2048 / 64, 24), 256, 0, stream>>>(xn, w1_l, b1 + l * 2048, nullptr, big, MROWS, 2048, 1024);
    mm_k<1><<<dim3(1024 / 64, 24), 256, 0, stream>>>(big, w2_l, b2 + l * 1024, x, x, MROWS, 1024, 2048);
  }

  postproc_k<<<dim3(32, 16), 256, 0, stream>>>(x, out);
}